// Round 4
// baseline (2017.008 us; speedup 1.0000x reference)
//
#include <hip/hip_runtime.h>
#include <math.h>

typedef unsigned short u16;
typedef short bf16x8 __attribute__((ext_vector_type(8)));
typedef float f32x4 __attribute__((ext_vector_type(4)));
typedef float f32x2 __attribute__((ext_vector_type(2)));

__device__ __forceinline__ float bf2f(u16 h) {
    union { unsigned u; float f; } v; v.u = ((unsigned)h) << 16; return v.f;
}
__device__ __forceinline__ u16 f2bf(float f) {
    union { float f; unsigned u; } v; v.f = f;
    unsigned r = v.u + 0x7fffu + ((v.u >> 16) & 1u);
    return (u16)(r >> 16);
}
__device__ __forceinline__ f32x2 up2(unsigned u) {
    union { unsigned v; float f; } lo, hi;
    lo.v = u << 16; hi.v = u & 0xffff0000u;
    f32x2 r; r.x = lo.f; r.y = hi.f; return r;
}
__device__ __forceinline__ f32x2 unpk(unsigned u) { return up2(u); }
__device__ __forceinline__ f32x4 unpk(uint2 u) {
    f32x2 a = up2(u.x), b = up2(u.y);
    f32x4 r; r.x = a.x; r.y = a.y; r.z = b.x; r.w = b.y; return r;
}
__device__ __forceinline__ unsigned pkbf(f32x2 v) {
    return (unsigned)f2bf(v.x) | ((unsigned)f2bf(v.y) << 16);
}
__device__ __forceinline__ uint2 pkbf(f32x4 v) {
    uint2 r;
    r.x = (unsigned)f2bf(v.x) | ((unsigned)f2bf(v.y) << 16);
    r.y = (unsigned)f2bf(v.z) | ((unsigned)f2bf(v.w) << 16);
    return r;
}
__device__ __forceinline__ float gl(float v) {
    return 0.5f * v * (1.f + erff(v * 0.70710678118654752f));
}

// async global->LDS 16B: LDS dest must be wave-uniform; HW adds lane*16
__device__ __forceinline__ void gload_lds16(const u16* g, u16* l) {
    __builtin_amdgcn_global_load_lds(
        (const __attribute__((address_space(1))) void*)g,
        (__attribute__((address_space(3))) void*)l, 16, 0, 0);
}

template<int N> struct VecT;
template<> struct VecT<2> { typedef f32x2 T; typedef unsigned U; };
template<> struct VecT<4> { typedef f32x4 T; typedef uint2 U; };

#define CH    512
#define NPIX  16384
#define PTOT  32768
#define NHEAD 8

// ---------------- fp32 transpose [R][Cc] -> [Cc][R] per z slab ----------------
__global__ void transpose_k(const float* __restrict__ in, float* outF, u16* outB,
                            int R, int Cc, size_t ibs, size_t obs)
{
    __shared__ float tile[32][33];
    int z = blockIdx.z;
    const float* ip = in + (size_t)z * ibs;
    int c0 = blockIdx.x * 32, r0 = blockIdx.y * 32;
    int tx = threadIdx.x, ty = threadIdx.y;
#pragma unroll
    for (int j = 0; j < 4; j++)
        tile[ty + j * 8][tx] = ip[(size_t)(r0 + ty + j * 8) * Cc + c0 + tx];
    __syncthreads();
#pragma unroll
    for (int j = 0; j < 4; j++) {
        int orow = c0 + ty + j * 8, ocol = r0 + tx;
        float v = tile[tx][ty + j * 8];
        size_t o = (size_t)z * obs + (size_t)orow * R + ocol;
        if (outF) outF[o] = v;
        if (outB) outB[o] = f2bf(v);
    }
}

// ---------------- bf16 transpose [R][Cc] -> [Cc][R] per z slab ----------------
__global__ void transpose16_k(const u16* __restrict__ in, u16* __restrict__ out,
                              int R, int Cc, size_t ibs, size_t obs)
{
    __shared__ u16 tile[32][34];
    int z = blockIdx.z;
    const u16* ip = in + (size_t)z * ibs;
    int c0 = blockIdx.x * 32, r0 = blockIdx.y * 32;
    int tx = threadIdx.x, ty = threadIdx.y;
#pragma unroll
    for (int j = 0; j < 4; j++)
        tile[ty + j * 8][tx] = ip[(size_t)(r0 + ty + j * 8) * Cc + c0 + tx];
    __syncthreads();
#pragma unroll
    for (int j = 0; j < 4; j++)
        out[(size_t)z * obs + (size_t)(c0 + ty + j * 8) * R + r0 + tx] = tile[tx][ty + j * 8];
}

// ---------------- fp32 -> bf16 convert (4 elems/thread) ----------------
__global__ void cvt_bf16_k(const float* __restrict__ in, u16* __restrict__ out)
{
    size_t i = ((size_t)blockIdx.x * 256 + threadIdx.x) * 4;
    float4 v = *(const float4*)&in[i];
    uint2 st;
    st.x = (unsigned)f2bf(v.x) | ((unsigned)f2bf(v.y) << 16);
    st.y = (unsigned)f2bf(v.z) | ((unsigned)f2bf(v.w) << 16);
    *(uint2*)&out[i] = st;
}

// ---------------- w2 convert with group-0 (1+dw1[c]) column prescale ----------
__global__ void cvtw2_k(const float* __restrict__ in, const float* __restrict__ dw1,
                        u16* __restrict__ out)
{
    size_t i = ((size_t)blockIdx.x * 256 + threadIdx.x) * 4;   // over 2*512*2048
    int c = (int)(i & 2047);
    int l = (int)(i >> 20);
    float4 v = *(const float4*)&in[i];
    if (c < 512) {
        v.x *= 1.f + dw1[l * 512 + c];
        v.y *= 1.f + dw1[l * 512 + c + 1];
        v.z *= 1.f + dw1[l * 512 + c + 2];
        v.w *= 1.f + dw1[l * 512 + c + 3];
    }
    uint2 st;
    st.x = (unsigned)f2bf(v.x) | ((unsigned)f2bf(v.y) << 16);
    st.y = (unsigned)f2bf(v.z) | ((unsigned)f2bf(v.w) << 16);
    *(uint2*)&out[i] = st;
}

// ---------------- bf16 NT GEMM: out[i,o] = sum_k A[i,k]*B[o,k] ----------------
// 3-deep pipelined: 3 LDS buffers, counted s_waitcnt vmcnt(NLD) + raw s_barrier
// (tiles s+1, s+2 stay in flight across the barrier; 2-iteration latency
// window). Every iteration issues exactly one STAGE (tail iters issue a
// clamped dummy into a dead buffer) so the vmcnt arithmetic stays uniform.
// LDS slot-XOR swizzle (inverse swizzle on global source) -> conflict-free.
template<int TM>
__global__ __launch_bounds__(256) void gemm_nt_k(
    const u16* __restrict__ A, const u16* __restrict__ Bw,
    int K, int ldb, int Nn, int rowsPerBatch, int bStride, int kChunk,
    const float* __restrict__ bias, const float* resid,
    float* outF, u16* outB)
{
    constexpr int MT = TM / 32;          // m-frags per wave
    __shared__ u16 As[3][TM * 32];
    __shared__ u16 Bs[3][128 * 32];
    int tid = threadIdx.x;
    int rowBase = blockIdx.y * TM, colBase = blockIdx.x * 128;
    const u16* Bp = Bw + (size_t)(rowBase / rowsPerBatch) * bStride;

    int kb = 0, ke = K;
    float* outFp = outF;
    if (kChunk) {
        kb = blockIdx.z * kChunk; ke = kb + kChunk;
        outFp = outF + (size_t)blockIdx.z * (size_t)gridDim.y * TM * Nn;
    }

    f32x4 acc[MT][4] = {};
    int lane = tid & 63, wave = tid >> 6;
    int wr = wave >> 1, wc = wave & 1;
    int lm = lane & 15, lk = lane >> 4;

    int row0 = tid >> 2;                       // rows 0..63
    int kc   = ((tid ^ (tid >> 3)) & 3) * 8;   // pre-swizzled source k-slot
    int lb0  = (tid & ~63) * 8;                // wave-uniform LDS elem base

    const size_t aR0 = (size_t)(rowBase + row0) * K;
    const size_t bR0 = (size_t)(colBase + row0) * ldb;
    const size_t aR1 = (size_t)(rowBase + 64 + row0) * K;       // TM=128 only
    const size_t bR1 = (size_t)(colBase + 64 + row0) * ldb;

    auto STAGE = [&](int bsel, int k0) {
        gload_lds16(&A [aR0 + k0 + kc], &As[bsel][lb0]);
        gload_lds16(&Bp[bR0 + k0 + kc], &Bs[bsel][lb0]);
        if constexpr (TM == 128)
            gload_lds16(&A [aR1 + k0 + kc], &As[bsel][lb0 + 2048]);
        gload_lds16(&Bp[bR1 + k0 + kc], &Bs[bsel][lb0 + 2048]);
    };

    const int nsteps = (ke - kb) >> 5;
    STAGE(0, kb);
    STAGE(1, kb + 32);
    const int sl = (lk ^ ((lm >> 1) & 3)) * 8;   // swizzled read slot

    for (int s = 0; s < nsteps; ++s) {
        // tile s landed everywhere; tiles s+1, s+2 ride through the barrier
        if constexpr (TM == 128)
            asm volatile("s_waitcnt vmcnt(4)" ::: "memory");
        else
            asm volatile("s_waitcnt vmcnt(3)" ::: "memory");
        __builtin_amdgcn_s_barrier();
        __builtin_amdgcn_sched_barrier(0);
        // prefetch tile s+2 (clamped dummy keeps the vmcnt count uniform;
        // dummy writes a buffer not referenced again)
        int kpf = kb + ((s + 2 < nsteps) ? (s + 2) : (nsteps - 1)) * 32;
        STAGE((s + 2) % 3, kpf);

        const u16* Ab = &As[s % 3][0];
        const u16* Bb = &Bs[s % 3][0];
        bf16x8 af[MT], bfr[4];
#pragma unroll
        for (int mt = 0; mt < MT; mt++)
            af[mt] = *(const bf16x8*)&Ab[(wr * (TM / 2) + mt * 16 + lm) * 32 + sl];
#pragma unroll
        for (int nt = 0; nt < 4; nt++)
            bfr[nt] = *(const bf16x8*)&Bb[(wc * 64 + nt * 16 + lm) * 32 + sl];
        __builtin_amdgcn_s_setprio(1);
#pragma unroll
        for (int mt = 0; mt < MT; mt++)
#pragma unroll
            for (int nt = 0; nt < 4; nt++)
                acc[mt][nt] = __builtin_amdgcn_mfma_f32_16x16x32_bf16(
                    af[mt], bfr[nt], acc[mt][nt], 0, 0, 0);
        __builtin_amdgcn_s_setprio(0);
    }

#pragma unroll
    for (int mt = 0; mt < MT; mt++)
#pragma unroll
        for (int nt = 0; nt < 4; nt++) {
            int col = colBase + wc * 64 + nt * 16 + lm;
            float bv = bias ? bias[col] : 0.f;
#pragma unroll
            for (int r = 0; r < 4; r++) {
                int row = rowBase + wr * (TM / 2) + mt * 16 + lk * 4 + r;
                size_t o = (size_t)row * Nn + col;
                float v = acc[mt][nt][r] + bv;
                if (resid) v += resid[o];
                if (outFp) outFp[o] = v;
                if (outB) outB[o] = f2bf(v);
            }
        }
}

// ---------------- reduce 8 split-K partials -> bf16 ----------------
__global__ void sreduce_k(const float* __restrict__ Sp, u16* __restrict__ Sbf)
{
    int i = blockIdx.x * 256 + threadIdx.x;
    float s = 0.f;
#pragma unroll
    for (int z = 0; z < 8; z++) s += Sp[(size_t)z * 524288 + i];
    Sbf[i] = f2bf(s);
}

// ---------------- inv l2 norms ----------------
__global__ void nrm_k(const float* __restrict__ w, const float* __restrict__ Tf,
                      float* __restrict__ inv)
{
    int idx = blockIdx.x * 256 + threadIdx.x;   // 0..2047
    int e = idx & 511, b = idx >> 9;
    float s = 0.f;
    for (int c = 0; c < 512; c++)
        s += w[c * 512 + e] * Tf[(size_t)(b * 512 + c) * 512 + e];
    s = fmaxf(s, 0.f);
    inv[b * 512 + e] = 1.f / fmaxf(sqrtf(s), 1e-12f);
}

// ---------------- G[b,h,d,e]=sum_c T2[b,c,h64+d]*Wq[c,h64+e]; scale+softmax ----
__global__ __launch_bounds__(256) void gsmall_k(
    const float* __restrict__ T2f, const float* __restrict__ Wq,
    const float* __restrict__ qinv, const float* __restrict__ kinv,
    const float* __restrict__ resc, float* __restrict__ att)
{
    __shared__ float t2l[64][64], wql[64][64];
    int t = threadIdx.x, h = blockIdx.x, b = blockIdx.y;
    int e = t & 63, g4 = t >> 6;
    float acc[16];
#pragma unroll
    for (int r = 0; r < 16; r++) acc[r] = 0.f;
    for (int c0 = 0; c0 < 512; c0 += 64) {
        __syncthreads();
        for (int i = t; i < 4096; i += 256) {
            int cc = i >> 6, j = i & 63;
            t2l[cc][j] = T2f[(size_t)(b * 512 + c0 + cc) * 512 + h * 64 + j];
            wql[cc][j] = Wq[(size_t)(c0 + cc) * 512 + h * 64 + j];
        }
        __syncthreads();
        for (int cc = 0; cc < 64; cc++) {
            float qv = wql[cc][e];
#pragma unroll
            for (int r = 0; r < 16; r++) acc[r] += t2l[cc][g4 * 16 + r] * qv;
        }
    }
    float qn = qinv[b * 512 + h * 64 + e];
    float rs = resc[h];
    float* ap = att + (size_t)(b * 8 + h) * 4096;
    for (int r = 0; r < 16; r++) {
        int d = g4 * 16 + r;
        float v = acc[r] * kinv[b * 512 + h * 64 + d] * qn * rs;
        float m = v;
        for (int off = 32; off; off >>= 1) m = fmaxf(m, __shfl_xor(m, off));
        float ev = expf(v - m);
        float s = ev;
        for (int off = 32; off; off >>= 1) s += __shfl_xor(s, off);
        ap[d * 64 + e] = ev / s;
    }
}

// ---------------- M[b] fold ----------------
__global__ __launch_bounds__(256) void mbuild_k(const float* __restrict__ attn,
                                                const float* __restrict__ projW,
                                                u16* Mnt)
{
    __shared__ float at[64][64];
    __shared__ float pw[64][64];
    int t = threadIdx.x;
    int h = blockIdx.x, b = blockIdx.y;
    int e = t & 63, g4 = t >> 6;
    const float* ap = attn + (size_t)(b * NHEAD + h) * 4096;
    for (int i = t; i < 4096; i += 256) at[i >> 6][i & 63] = ap[i];
    for (int ot = 0; ot < 8; ot++) {
        __syncthreads();
        for (int i = t; i < 4096; i += 256)
            pw[i >> 6][i & 63] = projW[(size_t)(h * 64 + (i >> 6)) * CH + ot * 64 + (i & 63)];
        __syncthreads();
        float acc[16];
#pragma unroll
        for (int r = 0; r < 16; r++) acc[r] = 0.f;
        for (int dd = 0; dd < 64; dd++) {
            float av = at[dd][e];
#pragma unroll
            for (int r = 0; r < 16; r++) acc[r] += av * pw[dd][g4 * 16 + r];
        }
#pragma unroll
        for (int r = 0; r < 16; r++)
            Mnt[(size_t)b * (CH * CH) + (size_t)(ot * 64 + g4 * 16 + r) * CH + h * 64 + e]
                = f2bf(acc[r]);
        __syncthreads();
    }
}

// ============ register-sliding-window NHWC depthwise conv (pipelined) ============
// SI/SO: input/output channel strides (512 for [n][512] buffers, 1024 for Y2
// column-half writes). Channels are always 0..511.
template<int KS, int YS, int CPT, bool GELU_F, bool RESID, bool ACC, int SI, int SO>
__global__ __launch_bounds__(256, 1) void dwreg_k(
    const u16* __restrict__ in, const float* __restrict__ w,
    u16* __restrict__ outB, float* __restrict__ outAdd)
{
    constexpr int PAD = KS / 2;
    typedef typename VecT<CPT>::T fv;
    typedef typename VecT<CPT>::U uv;
    const int tid = threadIdx.x;
    const int cbase = (CPT == 4) ? ((tid & 127) * 4) : (tid * 2);
    const int x     = (CPT == 4) ? ((int)blockIdx.x * 2 + (tid >> 7)) : (int)blockIdx.x;
    const int y0 = blockIdx.y * YS;
    const int b  = blockIdx.z;
    const size_t bi = (size_t)b * NPIX * SI + cbase;
    const size_t bo = (size_t)b * NPIX * SO + cbase;

    fv wv[KS * KS];
#pragma unroll
    for (int t = 0; t < KS * KS; t++) {
        fv vv;
        vv.x = w[(cbase + 0) * KS * KS + t];
        vv.y = w[(cbase + 1) * KS * KS + t];
        if constexpr (CPT == 4) {
            vv.z = w[(cbase + 2) * KS * KS + t];
            vv.w = w[(cbase + 3) * KS * KS + t];
        }
        wv[t] = vv;
    }

    fv win[KS][KS];
    uv tmp[KS];

    auto rowload = [&](int t) {
        int yy = y0 - PAD + t;
        bool rv = ((unsigned)yy < 128u);
#pragma unroll
        for (int kx = 0; kx < KS; kx++) {
            int xx = x + kx - PAD;
            uv u = {};
            if (rv && ((unsigned)xx < 128u))
                u = *(const uv*)&in[bi + ((size_t)yy * 128 + xx) * SI];
            tmp[kx] = u;
        }
    };
    auto unpackrow = [&](int slot) {
#pragma unroll
        for (int kx = 0; kx < KS; kx++) win[slot][kx] = unpk(tmp[kx]);
    };

#pragma unroll
    for (int t = 0; t < KS - 1; t++) { rowload(t); unpackrow(t); }
    rowload(KS - 1);

    for (int i0 = 0; i0 < YS; i0 += KS) {
#pragma unroll
        for (int j = 0; j < KS; j++) {
            int i = i0 + j;
            if (i >= YS) break;
            unpackrow((j + KS - 1) % KS);
            if (i < YS - 1) rowload(i + KS);
            fv r = {};
#pragma unroll
            for (int ky = 0; ky < KS; ky++)
#pragma unroll
                for (int kx = 0; kx < KS; kx++)
                    r += win[(j + ky) % KS][kx] * wv[ky * KS + kx];
            if (GELU_F) {
                r.x = gl(r.x); r.y = gl(r.y);
                if constexpr (CPT == 4) { r.z = gl(r.z); r.w = gl(r.w); }
            }
            if (RESID) r += win[(j + PAD) % KS][PAD];
            size_t opos = bo + ((size_t)(y0 + i) * 128 + x) * SO;
            if (ACC) {
                fv* p = (fv*)&outAdd[opos];
                *p = *p + r;
            } else {
                uv pk = pkbf(r);
                *(uv*)&outB[opos] = pk;
            }
        }
    }
}

// ---------------- LayerNorm over c=512 per pixel, bf16 out ----------------
__global__ void ln_k(const float* __restrict__ xf, const float* __restrict__ g,
                     const float* __restrict__ bb, u16* __restrict__ xn)
{
    int t = threadIdx.x, lane = t & 63, wv = t >> 6;
    size_t pix = (size_t)blockIdx.x * 4 + wv;
    const float* row = xf + pix * CH;
    float4 a = *(const float4*)&row[lane * 8];
    float4 c = *(const float4*)&row[lane * 8 + 4];
    float s = a.x + a.y + a.z + a.w + c.x + c.y + c.z + c.w;
    float sq = a.x * a.x + a.y * a.y + a.z * a.z + a.w * a.w
             + c.x * c.x + c.y * c.y + c.z * c.z + c.w * c.w;
    for (int off = 32; off; off >>= 1) {
        s  += __shfl_xor(s, off);
        sq += __shfl_xor(sq, off);
    }
    float mu = s * (1.f / 512.f);
    float var = fmaxf(sq * (1.f / 512.f) - mu * mu, 0.f);
    float inv = rsqrtf(var + 1e-5f);
    float vals[8] = {a.x, a.y, a.z, a.w, c.x, c.y, c.z, c.w};
    unsigned o[4];
#pragma unroll
    for (int j = 0; j < 4; j++) {
        int cix = lane * 8 + j * 2;
        float v0 = (vals[j * 2] - mu) * inv * g[cix] + bb[cix];
        float v1 = (vals[j * 2 + 1] - mu) * inv * g[cix + 1] + bb[cix + 1];
        o[j] = (unsigned)f2bf(v0) | ((unsigned)f2bf(v1) << 16);
    }
    *(uint4*)&xn[pix * CH + lane * 8] = make_uint4(o[0], o[1], o[2], o[3]);
}

// =====================================================================
extern "C" void kernel_launch(void* const* d_in, const int* in_sizes, int n_in,
                              void* d_out, int out_size, void* d_ws, size_t ws_size,
                              hipStream_t stream)
{
    (void)in_sizes; (void)n_in; (void)out_size; (void)ws_size;
    const float* x_in  = (const float*)d_in[0];
    const float* Wq    = (const float*)d_in[1];
    const float* Wk    = (const float*)d_in[2];
    const float* Wv    = (const float*)d_in[3];
    const float* resc  = (const float*)d_in[4];
    const float* projW = (const float*)d_in[5];
    const float* projB = (const float*)d_in[6];
    const float* posw1 = (const float*)d_in[7];
    const float* posw2 = (const float*)d_in[8];
    const float* lng   = (const float*)d_in[9];
    const float* lnb   = (const float*)d_in[10];
    const float* w1    = (const float*)d_in[11];
    const float* dw1   = (const float*)d_in[12];
    const float* dw3   = (const float*)d_in[13];
    const float* dw5   = (const float*)d_in[14];
    const float* dw7   = (const float*)d_in[15];
    const float* w2    = (const float*)d_in[16];
    float* out = (float*)d_out;
    char* ws = (char*)d_ws;

    // ---- d_ws layout (~119 MB) ----
    float* XF  = (float*)(ws + 0);               // 64 MB fp32 state [b,n,c]
    u16*   XBb = (u16*)  (ws + 67108864ull);     // 32 MB bf16 x / xn [b,n,c]
    u16*   WQt = (u16*)  (ws + 100663296ull);    // 1 MB [2][512][512]
    u16*   WKt = (u16*)  (ws + 101711872ull);    // 1 MB
    u16*   WVt = (u16*)  (ws + 102760448ull);    // 1 MB
    u16*   W1b = (u16*)  (ws + 103809024ull);    // 4 MB [2][2048][512]
    u16*   W2b = (u16*)  (ws + 108003328ull);    // 4 MB [2][512][2048]
    u16*   Mnt = (u16*)  (ws + 112197632ull);    // 1 MB [2][512][512]
    u16*   Sbf = (u16*)  (ws + 113246208ull);    // 1 MB [2][512][512]
    float* T1f = (float*)(ws + 114294784ull);    // 2 MB [2][512][512]
    float* T2f = (float*)(ws + 116391936ull);    // 2 MB
    float* QNI = (float*)(ws + 118489088ull);    // 4 KB [2][512]
    float* KNI = (float*)(ws + 118493184ull);    // 4 KB
    float* ATT = (float*)(ws + 118497280ull);    // 256 KB [2][8][64][64]

    // ---- d_out used as scratch until the final transpose ----
    u16*   R2  = (u16*)d_out;                    // 32 MB (attn phase)
    u16*   R3  = (u16*)d_out + 16777216;         // 32 MB (attn phase)
    float* Sp  = (float*)((char*)d_out + 33554432ull); // 16 MB split-K partials
    u16*   Y2  = (u16*)d_out;                    // FFN: [16384][1024] bf16 (32 MB)
    u16*   R3s = (u16*)d_out + 16777216;         // FFN: [16384][512] bf16 (16 MB)

    const int BIG = 1 << 30;
    dim3 tb(32, 8);

    // prep
    transpose_k<<<dim3(512, 16, 2), tb, 0, stream>>>(x_in, XF, XBb, 512, 16384, 8388608, 8388608);
    transpose_k<<<dim3(16, 16, 2), tb, 0, stream>>>(Wq, nullptr, WQt, 512, 512, 262144, 262144);
    transpose_k<<<dim3(16, 16, 2), tb, 0, stream>>>(Wk, nullptr, WKt, 512, 512, 262144, 262144);
    transpose_k<<<dim3(16, 16, 2), tb, 0, stream>>>(Wv, nullptr, WVt, 512, 512, 262144, 262144);
    cvt_bf16_k<<<2048, 256, 0, stream>>>(w1, W1b);
    cvtw2_k<<<2048, 256, 0, stream>>>(w2, dw1, W2b);

    for (int l = 0; l < 2; l++) {
        // XT (bf16 [b][c][n]) into R2
        if (l == 0)
            cvt_bf16_k<<<16384, 256, 0, stream>>>(x_in, R2);
        else
            transpose16_k<<<dim3(16, 512, 2), tb, 0, stream>>>(XBb, R2, 16384, 512, 8388608, 8388608);
        // S = X^T X per batch: split-K partials
        gemm_nt_k<128><<<dim3(4, 8, 8), 256, 0, stream>>>(R2, R2, 16384, 16384, 512,
            512, 8388608, 2048, nullptr, nullptr, Sp, nullptr);
        sreduce_k<<<2048, 256, 0, stream>>>(Sp, Sbf);
        // T1 = S*Wq, T2 = S*Wk
        gemm_nt_k<64><<<dim3(4, 16), 256, 0, stream>>>(Sbf, WQt + l * 262144, 512, 512, 512,
            BIG, 0, 0, nullptr, nullptr, T1f, nullptr);
        gemm_nt_k<64><<<dim3(4, 16), 256, 0, stream>>>(Sbf, WKt + l * 262144, 512, 512, 512,
            BIG, 0, 0, nullptr, nullptr, T2f, nullptr);
        nrm_k<<<8, 256, 0, stream>>>(Wq + l * 262144, T1f, QNI);
        nrm_k<<<8, 256, 0, stream>>>(Wk + l * 262144, T2f, KNI);
        gsmall_k<<<dim3(8, 2), 256, 0, stream>>>(T2f, Wq + l * 262144, QNI, KNI,
            resc + l * 8, ATT);
        mbuild_k<<<dim3(8, 2), 256, 0, stream>>>(ATT, projW + l * 262144, Mnt);
        // V = x @ Wv
        gemm_nt_k<64><<<dim3(4, 512), 256, 0, stream>>>(XBb, WVt + l * 262144, 512, 512, 512,
            BIG, 0, 0, nullptr, nullptr, nullptr, R3);
        // x += V @ M^T + proj_b
        gemm_nt_k<64><<<dim3(4, 512), 256, 0, stream>>>(R3, Mnt, 512, 512, 512,
            16384, 262144, 0, projB + l * 512, XF, XF, nullptr);
        // positional branch: dwconv3+gelu -> R2, then dwconv3 accumulated into XF
        dwreg_k<3, 16, 4, true, false, false, 512, 512><<<dim3(64, 8, 2), 256, 0, stream>>>(
            R3, posw1 + l * 4608, R2, nullptr);
        dwreg_k<3, 16, 4, false, false, true, 512, 512><<<dim3(64, 8, 2), 256, 0, stream>>>(
            R2, posw2 + l * 4608, nullptr, XF);
        // PreNorm
        ln_k<<<8192, 256, 0, stream>>>(XF, lng + l * 512, lnb + l * 512, XBb);
        // MS-FFN: per-batch slabs, groups merged in PAIRS into Y2 [16384][1024],
        // down-projection as K=1024 GEMMs (halves fp32 XF RMW passes).
        for (int b2 = 0; b2 < 2; b2++) {
            const size_t boff = (size_t)b2 * NPIX * 512;
            // ---- pair 0: g0 (1x1 folded into W2b prescale) + g1 (3x3) ----
            gemm_nt_k<64><<<dim3(4, 256), 256, 0, stream>>>(XBb + boff,
                W1b + l * 1048576 + 0 * 262144, 512, 512, 1024,
                BIG, 0, 0, nullptr, nullptr, nullptr, Y2);            // g0 -> Y2[:,0:512]
            gemm_nt_k<64><<<dim3(4, 256), 256, 0, stream>>>(XBb + boff,
                W1b + l * 1048576 + 1 * 262144, 512, 512, 512,
                BIG, 0, 0, nullptr, nullptr, nullptr, R3s);           // g1 -> R3s
            dwreg_k<3, 16, 4, false, true, false, 512, 1024><<<dim3(64, 8, 1), 256, 0, stream>>>(
                R3s, dw3 + l * 4608, Y2 + 512, nullptr);              // -> Y2[:,512:1024]
            gemm_nt_k<64><<<dim3(4, 256), 256, 0, stream>>>(Y2,
                W2b + l * 1048576 + 0, 1024, 2048, 512,
                BIG, 0, 0, nullptr, XF + boff, XF + boff, nullptr);   // down pair 0
            // ---- pair 1: g2 (5x5) + g3 (7x7) ----
            gemm_nt_k<64><<<dim3(4, 256), 256, 0, stream>>>(XBb + boff,
                W1b + l * 1048576 + 2 * 262144, 512, 512, 512,
                BIG, 0, 0, nullptr, nullptr, nullptr, R3s);           // g2 -> R3s
            dwreg_k<5, 16, 2, false, true, false, 512, 1024><<<dim3(128, 8, 1), 256, 0, stream>>>(
                R3s, dw5 + l * 12800, Y2 + 0, nullptr);               // -> Y2[:,0:512]
            gemm_nt_k<64><<<dim3(4, 256), 256, 0, stream>>>(XBb + boff,
                W1b + l * 1048576 + 3 * 262144, 512, 512, 512,
                BIG, 0, 0, nullptr, nullptr, nullptr, R3s);           // g3 -> R3s
            dwreg_k<7, 32, 2, false, true, false, 512, 1024><<<dim3(128, 4, 1), 256, 0, stream>>>(
                R3s, dw7 + l * 25088, Y2 + 512, nullptr);             // -> Y2[:,512:1024]
            gemm_nt_k<64><<<dim3(4, 256), 256, 0, stream>>>(Y2,
                W2b + l * 1048576 + 1024, 1024, 2048, 512,
                BIG, 0, 0, nullptr, XF + boff, XF + boff, XBb + boff); // down pair 1 (+raw-x bf16)
        }
    }
    // final: XF [b,n,c] -> out [b,c,n]
    transpose_k<<<dim3(16, 512, 2), tb, 0, stream>>>(XF, out, nullptr, 16384, 512, 8388608, 8388608);
}

// Round 5
// 1909.463 us; speedup vs baseline: 1.0563x; 1.0563x over previous
//
#include <hip/hip_runtime.h>
#include <math.h>

typedef unsigned short u16;
typedef short bf16x8 __attribute__((ext_vector_type(8)));
typedef float f32x4 __attribute__((ext_vector_type(4)));
typedef float f32x2 __attribute__((ext_vector_type(2)));

__device__ __forceinline__ float bf2f(u16 h) {
    union { unsigned u; float f; } v; v.u = ((unsigned)h) << 16; return v.f;
}
__device__ __forceinline__ u16 f2bf(float f) {
    union { float f; unsigned u; } v; v.f = f;
    unsigned r = v.u + 0x7fffu + ((v.u >> 16) & 1u);
    return (u16)(r >> 16);
}
__device__ __forceinline__ f32x2 up2(unsigned u) {
    union { unsigned v; float f; } lo, hi;
    lo.v = u << 16; hi.v = u & 0xffff0000u;
    f32x2 r; r.x = lo.f; r.y = hi.f; return r;
}
__device__ __forceinline__ f32x2 unpk(unsigned u) { return up2(u); }
__device__ __forceinline__ f32x4 unpk(uint2 u) {
    f32x2 a = up2(u.x), b = up2(u.y);
    f32x4 r; r.x = a.x; r.y = a.y; r.z = b.x; r.w = b.y; return r;
}
__device__ __forceinline__ unsigned pkbf(f32x2 v) {
    return (unsigned)f2bf(v.x) | ((unsigned)f2bf(v.y) << 16);
}
__device__ __forceinline__ uint2 pkbf(f32x4 v) {
    uint2 r;
    r.x = (unsigned)f2bf(v.x) | ((unsigned)f2bf(v.y) << 16);
    r.y = (unsigned)f2bf(v.z) | ((unsigned)f2bf(v.w) << 16);
    return r;
}
__device__ __forceinline__ float gl(float v) {
    return 0.5f * v * (1.f + erff(v * 0.70710678118654752f));
}

// async global->LDS 16B: LDS dest must be wave-uniform; HW adds lane*16
__device__ __forceinline__ void gload_lds16(const u16* g, u16* l) {
    __builtin_amdgcn_global_load_lds(
        (const __attribute__((address_space(1))) void*)g,
        (__attribute__((address_space(3))) void*)l, 16, 0, 0);
}

template<int N> struct VecT;
template<> struct VecT<2> { typedef f32x2 T; typedef unsigned U; };
template<> struct VecT<4> { typedef f32x4 T; typedef uint2 U; };

#define CH    512
#define NPIX  16384
#define PTOT  32768
#define NHEAD 8

// ---------------- fp32 transpose [R][Cc] -> [Cc][R] per z slab ----------------
__global__ void transpose_k(const float* __restrict__ in, float* outF, u16* outB,
                            int R, int Cc, size_t ibs, size_t obs)
{
    __shared__ float tile[32][33];
    int z = blockIdx.z;
    const float* ip = in + (size_t)z * ibs;
    int c0 = blockIdx.x * 32, r0 = blockIdx.y * 32;
    int tx = threadIdx.x, ty = threadIdx.y;
#pragma unroll
    for (int j = 0; j < 4; j++)
        tile[ty + j * 8][tx] = ip[(size_t)(r0 + ty + j * 8) * Cc + c0 + tx];
    __syncthreads();
#pragma unroll
    for (int j = 0; j < 4; j++) {
        int orow = c0 + ty + j * 8, ocol = r0 + tx;
        float v = tile[tx][ty + j * 8];
        size_t o = (size_t)z * obs + (size_t)orow * R + ocol;
        if (outF) outF[o] = v;
        if (outB) outB[o] = f2bf(v);
    }
}

// ---------------- bf16 transpose [R][Cc] -> [Cc][R] per z slab ----------------
__global__ void transpose16_k(const u16* __restrict__ in, u16* __restrict__ out,
                              int R, int Cc, size_t ibs, size_t obs)
{
    __shared__ u16 tile[32][34];
    int z = blockIdx.z;
    const u16* ip = in + (size_t)z * ibs;
    int c0 = blockIdx.x * 32, r0 = blockIdx.y * 32;
    int tx = threadIdx.x, ty = threadIdx.y;
#pragma unroll
    for (int j = 0; j < 4; j++)
        tile[ty + j * 8][tx] = ip[(size_t)(r0 + ty + j * 8) * Cc + c0 + tx];
    __syncthreads();
#pragma unroll
    for (int j = 0; j < 4; j++)
        out[(size_t)z * obs + (size_t)(c0 + ty + j * 8) * R + r0 + tx] = tile[tx][ty + j * 8];
}

// ---------------- fp32 -> bf16 convert (4 elems/thread) ----------------
__global__ void cvt_bf16_k(const float* __restrict__ in, u16* __restrict__ out)
{
    size_t i = ((size_t)blockIdx.x * 256 + threadIdx.x) * 4;
    float4 v = *(const float4*)&in[i];
    uint2 st;
    st.x = (unsigned)f2bf(v.x) | ((unsigned)f2bf(v.y) << 16);
    st.y = (unsigned)f2bf(v.z) | ((unsigned)f2bf(v.w) << 16);
    *(uint2*)&out[i] = st;
}

// ---------------- w2 convert with group-0 (1+dw1[c]) column prescale ----------
__global__ void cvtw2_k(const float* __restrict__ in, const float* __restrict__ dw1,
                        u16* __restrict__ out)
{
    size_t i = ((size_t)blockIdx.x * 256 + threadIdx.x) * 4;   // over 2*512*2048
    int c = (int)(i & 2047);
    int l = (int)(i >> 20);
    float4 v = *(const float4*)&in[i];
    if (c < 512) {
        v.x *= 1.f + dw1[l * 512 + c];
        v.y *= 1.f + dw1[l * 512 + c + 1];
        v.z *= 1.f + dw1[l * 512 + c + 2];
        v.w *= 1.f + dw1[l * 512 + c + 3];
    }
    uint2 st;
    st.x = (unsigned)f2bf(v.x) | ((unsigned)f2bf(v.y) << 16);
    st.y = (unsigned)f2bf(v.z) | ((unsigned)f2bf(v.w) << 16);
    *(uint2*)&out[i] = st;
}

// ---------------- bf16 NT GEMM: out[i,o] = sum_k A[i,k]*B[o,k] ----------------
// 2-phase pipelined global_load_lds staging (r3 structure), LDS slot-XOR
// swizzle -> conflict-free staging/reads. TM==64 adds a vectorized epilogue:
// acc is transposed through a padded LDS tile (two 32-row halves reusing the
// staging LDS) so resid/outF/outB traffic is float4/uint2 coalesced instead of
// scalar dword RMW (the fp32 state RMW is 128 MB of the 167 MB per dispatch).
template<int TM>
__global__ __launch_bounds__(256) void gemm_nt_k(
    const u16* __restrict__ A, const u16* __restrict__ Bw,
    int K, int ldb, int Nn, int rowsPerBatch, int bStride, int kChunk,
    const float* __restrict__ bias, const float* resid,
    float* outF, u16* outB)
{
    constexpr int MT = TM / 32;          // m-frags per wave
    constexpr int ABUF = TM * 32;        // elems per A buffer
    __shared__ __attribute__((aligned(16))) u16 smem[2 * ABUF + 2 * 128 * 32];
    u16* Asb = smem;                     // [2][ABUF]
    u16* Bsb = smem + 2 * ABUF;          // [2][4096]
    int tid = threadIdx.x;
    int rowBase = blockIdx.y * TM, colBase = blockIdx.x * 128;
    const u16* Bp = Bw + (size_t)(rowBase / rowsPerBatch) * bStride;

    int kb = 0, ke = K;
    float* outFp = outF;
    if (kChunk) {
        kb = blockIdx.z * kChunk; ke = kb + kChunk;
        outFp = outF + (size_t)blockIdx.z * (size_t)gridDim.y * TM * Nn;
    }

    f32x4 acc[MT][4] = {};
    int lane = tid & 63, wave = tid >> 6;
    int wr = wave >> 1, wc = wave & 1;
    int lm = lane & 15, lk = lane >> 4;

    int row0 = tid >> 2;                       // rows 0..63
    int kc   = ((tid ^ (tid >> 3)) & 3) * 8;   // pre-swizzled source k-slot
    int lb0  = (tid & ~63) * 8;                // wave-uniform LDS elem base

    const size_t aR0 = (size_t)(rowBase + row0) * K;
    const size_t bR0 = (size_t)(colBase + row0) * ldb;
    const size_t aR1 = (size_t)(rowBase + 64 + row0) * K;       // TM=128 only
    const size_t bR1 = (size_t)(colBase + 64 + row0) * ldb;

    auto STAGE = [&](int bsel, int k0) {
        gload_lds16(&A [aR0 + k0 + kc], Asb + bsel * ABUF + lb0);
        gload_lds16(&Bp[bR0 + k0 + kc], Bsb + bsel * 4096 + lb0);
        if constexpr (TM == 128)
            gload_lds16(&A [aR1 + k0 + kc], Asb + bsel * ABUF + lb0 + 2048);
        gload_lds16(&Bp[bR1 + k0 + kc], Bsb + bsel * 4096 + lb0 + 2048);
    };

    STAGE(0, kb);
    __syncthreads();                 // tile 0 visible
    int buf = 0;
    const int sl = (lk ^ ((lm >> 1) & 3)) * 8;   // swizzled read slot

    for (int k0 = kb; k0 < ke; k0 += 32) {
        if (k0 + 32 < ke) STAGE(buf ^ 1, k0 + 32);   // prefetch next tile
        const u16* Ab = Asb + buf * ABUF;
        const u16* Bb = Bsb + buf * 4096;
        bf16x8 af[MT], bfr[4];
#pragma unroll
        for (int mt = 0; mt < MT; mt++)
            af[mt] = *(const bf16x8*)&Ab[(wr * (TM / 2) + mt * 16 + lm) * 32 + sl];
#pragma unroll
        for (int nt = 0; nt < 4; nt++)
            bfr[nt] = *(const bf16x8*)&Bb[(wc * 64 + nt * 16 + lm) * 32 + sl];
#pragma unroll
        for (int mt = 0; mt < MT; mt++)
#pragma unroll
            for (int nt = 0; nt < 4; nt++)
                acc[mt][nt] = __builtin_amdgcn_mfma_f32_16x16x32_bf16(
                    af[mt], bfr[nt], acc[mt][nt], 0, 0, 0);
        __syncthreads();             // prefetch landed + all reads of buf done
        buf ^= 1;
    }

    if constexpr (TM == 64) {
        // ---- vectorized epilogue: LDS transpose, two 32-row halves ----
        float* smf = (float*)smem;              // 32 x 132 fp32 = 16896 B
        const int erow = tid >> 5;              // 0..7
        const int ecol = (tid & 31) * 4;        // 0,4,..124
        for (int hf = 0; hf < 2; ++hf) {
            __syncthreads();
            if (wr == hf) {
#pragma unroll
                for (int mt = 0; mt < MT; mt++)
#pragma unroll
                    for (int nt = 0; nt < 4; nt++) {
                        int lr = mt * 16 + lk * 4;
                        int lc = wc * 64 + nt * 16 + lm;
#pragma unroll
                        for (int r = 0; r < 4; r++)
                            smf[(lr + r) * 132 + lc] = acc[mt][nt][r];
                    }
            }
            __syncthreads();
#pragma unroll
            for (int p = 0; p < 4; p++) {
                int lrow = erow + p * 8;                    // 0..31
                int grow = rowBase + hf * 32 + lrow;
                int gcol = colBase + ecol;
                f32x4 v = *(f32x4*)&smf[lrow * 132 + ecol];
                if (bias) {
                    v.x += bias[gcol];     v.y += bias[gcol + 1];
                    v.z += bias[gcol + 2]; v.w += bias[gcol + 3];
                }
                size_t o = (size_t)grow * Nn + gcol;
                if (resid) { f32x4 rv = *(const f32x4*)&resid[o]; v += rv; }
                if (outFp) *(f32x4*)&outFp[o] = v;
                if (outB) { uint2 pk = pkbf(v); *(uint2*)&outB[o] = pk; }
            }
        }
    } else {
#pragma unroll
        for (int mt = 0; mt < MT; mt++)
#pragma unroll
            for (int nt = 0; nt < 4; nt++) {
                int col = colBase + wc * 64 + nt * 16 + lm;
                float bv = bias ? bias[col] : 0.f;
#pragma unroll
                for (int r = 0; r < 4; r++) {
                    int row = rowBase + wr * (TM / 2) + mt * 16 + lk * 4 + r;
                    size_t o = (size_t)row * Nn + col;
                    float v = acc[mt][nt][r] + bv;
                    if (resid) v += resid[o];
                    if (outFp) outFp[o] = v;
                    if (outB) outB[o] = f2bf(v);
                }
            }
    }
}

// ---------------- reduce 8 split-K partials -> bf16 ----------------
__global__ void sreduce_k(const float* __restrict__ Sp, u16* __restrict__ Sbf)
{
    int i = blockIdx.x * 256 + threadIdx.x;
    float s = 0.f;
#pragma unroll
    for (int z = 0; z < 8; z++) s += Sp[(size_t)z * 524288 + i];
    Sbf[i] = f2bf(s);
}

// ---------------- inv l2 norms ----------------
__global__ void nrm_k(const float* __restrict__ w, const float* __restrict__ Tf,
                      float* __restrict__ inv)
{
    int idx = blockIdx.x * 256 + threadIdx.x;   // 0..2047
    int e = idx & 511, b = idx >> 9;
    float s = 0.f;
    for (int c = 0; c < 512; c++)
        s += w[c * 512 + e] * Tf[(size_t)(b * 512 + c) * 512 + e];
    s = fmaxf(s, 0.f);
    inv[b * 512 + e] = 1.f / fmaxf(sqrtf(s), 1e-12f);
}

// ---------------- G[b,h,d,e]=sum_c T2[b,c,h64+d]*Wq[c,h64+e]; scale+softmax ----
__global__ __launch_bounds__(256) void gsmall_k(
    const float* __restrict__ T2f, const float* __restrict__ Wq,
    const float* __restrict__ qinv, const float* __restrict__ kinv,
    const float* __restrict__ resc, float* __restrict__ att)
{
    __shared__ float t2l[64][64], wql[64][64];
    int t = threadIdx.x, h = blockIdx.x, b = blockIdx.y;
    int e = t & 63, g4 = t >> 6;
    float acc[16];
#pragma unroll
    for (int r = 0; r < 16; r++) acc[r] = 0.f;
    for (int c0 = 0; c0 < 512; c0 += 64) {
        __syncthreads();
        for (int i = t; i < 4096; i += 256) {
            int cc = i >> 6, j = i & 63;
            t2l[cc][j] = T2f[(size_t)(b * 512 + c0 + cc) * 512 + h * 64 + j];
            wql[cc][j] = Wq[(size_t)(c0 + cc) * 512 + h * 64 + j];
        }
        __syncthreads();
        for (int cc = 0; cc < 64; cc++) {
            float qv = wql[cc][e];
#pragma unroll
            for (int r = 0; r < 16; r++) acc[r] += t2l[cc][g4 * 16 + r] * qv;
        }
    }
    float qn = qinv[b * 512 + h * 64 + e];
    float rs = resc[h];
    float* ap = att + (size_t)(b * 8 + h) * 4096;
    for (int r = 0; r < 16; r++) {
        int d = g4 * 16 + r;
        float v = acc[r] * kinv[b * 512 + h * 64 + d] * qn * rs;
        float m = v;
        for (int off = 32; off; off >>= 1) m = fmaxf(m, __shfl_xor(m, off));
        float ev = expf(v - m);
        float s = ev;
        for (int off = 32; off; off >>= 1) s += __shfl_xor(s, off);
        ap[d * 64 + e] = ev / s;
    }
}

// ---------------- M[b] fold ----------------
__global__ __launch_bounds__(256) void mbuild_k(const float* __restrict__ attn,
                                                const float* __restrict__ projW,
                                                u16* Mnt)
{
    __shared__ float at[64][64];
    __shared__ float pw[64][64];
    int t = threadIdx.x;
    int h = blockIdx.x, b = blockIdx.y;
    int e = t & 63, g4 = t >> 6;
    const float* ap = attn + (size_t)(b * NHEAD + h) * 4096;
    for (int i = t; i < 4096; i += 256) at[i >> 6][i & 63] = ap[i];
    for (int ot = 0; ot < 8; ot++) {
        __syncthreads();
        for (int i = t; i < 4096; i += 256)
            pw[i >> 6][i & 63] = projW[(size_t)(h * 64 + (i >> 6)) * CH + ot * 64 + (i & 63)];
        __syncthreads();
        float acc[16];
#pragma unroll
        for (int r = 0; r < 16; r++) acc[r] = 0.f;
        for (int dd = 0; dd < 64; dd++) {
            float av = at[dd][e];
#pragma unroll
            for (int r = 0; r < 16; r++) acc[r] += av * pw[dd][g4 * 16 + r];
        }
#pragma unroll
        for (int r = 0; r < 16; r++)
            Mnt[(size_t)b * (CH * CH) + (size_t)(ot * 64 + g4 * 16 + r) * CH + h * 64 + e]
                = f2bf(acc[r]);
        __syncthreads();
    }
}

// ============ register-sliding-window NHWC depthwise conv (pipelined) ============
// SI/SO: input/output channel strides (512 for [n][512] buffers, 1024 for Y2
// column-half writes). Channels are always 0..511.
template<int KS, int YS, int CPT, bool GELU_F, bool RESID, bool ACC, int SI, int SO>
__global__ __launch_bounds__(256, 1) void dwreg_k(
    const u16* __restrict__ in, const float* __restrict__ w,
    u16* __restrict__ outB, float* __restrict__ outAdd)
{
    constexpr int PAD = KS / 2;
    typedef typename VecT<CPT>::T fv;
    typedef typename VecT<CPT>::U uv;
    const int tid = threadIdx.x;
    const int cbase = (CPT == 4) ? ((tid & 127) * 4) : (tid * 2);
    const int x     = (CPT == 4) ? ((int)blockIdx.x * 2 + (tid >> 7)) : (int)blockIdx.x;
    const int y0 = blockIdx.y * YS;
    const int b  = blockIdx.z;
    const size_t bi = (size_t)b * NPIX * SI + cbase;
    const size_t bo = (size_t)b * NPIX * SO + cbase;

    fv wv[KS * KS];
#pragma unroll
    for (int t = 0; t < KS * KS; t++) {
        fv vv;
        vv.x = w[(cbase + 0) * KS * KS + t];
        vv.y = w[(cbase + 1) * KS * KS + t];
        if constexpr (CPT == 4) {
            vv.z = w[(cbase + 2) * KS * KS + t];
            vv.w = w[(cbase + 3) * KS * KS + t];
        }
        wv[t] = vv;
    }

    fv win[KS][KS];
    uv tmp[KS];

    auto rowload = [&](int t) {
        int yy = y0 - PAD + t;
        bool rv = ((unsigned)yy < 128u);
#pragma unroll
        for (int kx = 0; kx < KS; kx++) {
            int xx = x + kx - PAD;
            uv u = {};
            if (rv && ((unsigned)xx < 128u))
                u = *(const uv*)&in[bi + ((size_t)yy * 128 + xx) * SI];
            tmp[kx] = u;
        }
    };
    auto unpackrow = [&](int slot) {
#pragma unroll
        for (int kx = 0; kx < KS; kx++) win[slot][kx] = unpk(tmp[kx]);
    };

#pragma unroll
    for (int t = 0; t < KS - 1; t++) { rowload(t); unpackrow(t); }
    rowload(KS - 1);

    for (int i0 = 0; i0 < YS; i0 += KS) {
#pragma unroll
        for (int j = 0; j < KS; j++) {
            int i = i0 + j;
            if (i >= YS) break;
            unpackrow((j + KS - 1) % KS);
            if (i < YS - 1) rowload(i + KS);
            fv r = {};
#pragma unroll
            for (int ky = 0; ky < KS; ky++)
#pragma unroll
                for (int kx = 0; kx < KS; kx++)
                    r += win[(j + ky) % KS][kx] * wv[ky * KS + kx];
            if (GELU_F) {
                r.x = gl(r.x); r.y = gl(r.y);
                if constexpr (CPT == 4) { r.z = gl(r.z); r.w = gl(r.w); }
            }
            if (RESID) r += win[(j + PAD) % KS][PAD];
            size_t opos = bo + ((size_t)(y0 + i) * 128 + x) * SO;
            if (ACC) {
                fv* p = (fv*)&outAdd[opos];
                *p = *p + r;
            } else {
                uv pk = pkbf(r);
                *(uv*)&outB[opos] = pk;
            }
        }
    }
}

// ---------------- LayerNorm over c=512 per pixel, bf16 out ----------------
__global__ void ln_k(const float* __restrict__ xf, const float* __restrict__ g,
                     const float* __restrict__ bb, u16* __restrict__ xn)
{
    int t = threadIdx.x, lane = t & 63, wv = t >> 6;
    size_t pix = (size_t)blockIdx.x * 4 + wv;
    const float* row = xf + pix * CH;
    float4 a = *(const float4*)&row[lane * 8];
    float4 c = *(const float4*)&row[lane * 8 + 4];
    float s = a.x + a.y + a.z + a.w + c.x + c.y + c.z + c.w;
    float sq = a.x * a.x + a.y * a.y + a.z * a.z + a.w * a.w
             + c.x * c.x + c.y * c.y + c.z * c.z + c.w * c.w;
    for (int off = 32; off; off >>= 1) {
        s  += __shfl_xor(s, off);
        sq += __shfl_xor(sq, off);
    }
    float mu = s * (1.f / 512.f);
    float var = fmaxf(sq * (1.f / 512.f) - mu * mu, 0.f);
    float inv = rsqrtf(var + 1e-5f);
    float vals[8] = {a.x, a.y, a.z, a.w, c.x, c.y, c.z, c.w};
    unsigned o[4];
#pragma unroll
    for (int j = 0; j < 4; j++) {
        int cix = lane * 8 + j * 2;
        float v0 = (vals[j * 2] - mu) * inv * g[cix] + bb[cix];
        float v1 = (vals[j * 2 + 1] - mu) * inv * g[cix + 1] + bb[cix + 1];
        o[j] = (unsigned)f2bf(v0) | ((unsigned)f2bf(v1) << 16);
    }
    *(uint4*)&xn[pix * CH + lane * 8] = make_uint4(o[0], o[1], o[2], o[3]);
}

// =====================================================================
extern "C" void kernel_launch(void* const* d_in, const int* in_sizes, int n_in,
                              void* d_out, int out_size, void* d_ws, size_t ws_size,
                              hipStream_t stream)
{
    (void)in_sizes; (void)n_in; (void)out_size; (void)ws_size;
    const float* x_in  = (const float*)d_in[0];
    const float* Wq    = (const float*)d_in[1];
    const float* Wk    = (const float*)d_in[2];
    const float* Wv    = (const float*)d_in[3];
    const float* resc  = (const float*)d_in[4];
    const float* projW = (const float*)d_in[5];
    const float* projB = (const float*)d_in[6];
    const float* posw1 = (const float*)d_in[7];
    const float* posw2 = (const float*)d_in[8];
    const float* lng   = (const float*)d_in[9];
    const float* lnb   = (const float*)d_in[10];
    const float* w1    = (const float*)d_in[11];
    const float* dw1   = (const float*)d_in[12];
    const float* dw3   = (const float*)d_in[13];
    const float* dw5   = (const float*)d_in[14];
    const float* dw7   = (const float*)d_in[15];
    const float* w2    = (const float*)d_in[16];
    float* out = (float*)d_out;
    char* ws = (char*)d_ws;

    // ---- d_ws layout (~119 MB) ----
    float* XF  = (float*)(ws + 0);               // 64 MB fp32 state [b,n,c]
    u16*   XBb = (u16*)  (ws + 67108864ull);     // 32 MB bf16 x / xn [b,n,c]
    u16*   WQt = (u16*)  (ws + 100663296ull);    // 1 MB [2][512][512]
    u16*   WKt = (u16*)  (ws + 101711872ull);    // 1 MB
    u16*   WVt = (u16*)  (ws + 102760448ull);    // 1 MB
    u16*   W1b = (u16*)  (ws + 103809024ull);    // 4 MB [2][2048][512]
    u16*   W2b = (u16*)  (ws + 108003328ull);    // 4 MB [2][512][2048]
    u16*   Mnt = (u16*)  (ws + 112197632ull);    // 1 MB [2][512][512]
    u16*   Sbf = (u16*)  (ws + 113246208ull);    // 1 MB [2][512][512]
    float* T1f = (float*)(ws + 114294784ull);    // 2 MB [2][512][512]
    float* T2f = (float*)(ws + 116391936ull);    // 2 MB
    float* QNI = (float*)(ws + 118489088ull);    // 4 KB [2][512]
    float* KNI = (float*)(ws + 118493184ull);    // 4 KB
    float* ATT = (float*)(ws + 118497280ull);    // 256 KB [2][8][64][64]

    // ---- d_out used as scratch until the final transpose ----
    u16*   R2  = (u16*)d_out;                    // 32 MB (attn phase)
    u16*   R3  = (u16*)d_out + 16777216;         // 32 MB (attn phase)
    float* Sp  = (float*)((char*)d_out + 33554432ull); // 16 MB split-K partials
    u16*   Y2  = (u16*)d_out;                    // FFN: [16384][1024] bf16 (32 MB)
    u16*   R3s = (u16*)d_out + 16777216;         // FFN: [16384][512] bf16 (16 MB)

    const int BIG = 1 << 30;
    dim3 tb(32, 8);

    // prep
    transpose_k<<<dim3(512, 16, 2), tb, 0, stream>>>(x_in, XF, XBb, 512, 16384, 8388608, 8388608);
    transpose_k<<<dim3(16, 16, 2), tb, 0, stream>>>(Wq, nullptr, WQt, 512, 512, 262144, 262144);
    transpose_k<<<dim3(16, 16, 2), tb, 0, stream>>>(Wk, nullptr, WKt, 512, 512, 262144, 262144);
    transpose_k<<<dim3(16, 16, 2), tb, 0, stream>>>(Wv, nullptr, WVt, 512, 512, 262144, 262144);
    cvt_bf16_k<<<2048, 256, 0, stream>>>(w1, W1b);
    cvtw2_k<<<2048, 256, 0, stream>>>(w2, dw1, W2b);

    for (int l = 0; l < 2; l++) {
        // XT (bf16 [b][c][n]) into R2
        if (l == 0)
            cvt_bf16_k<<<16384, 256, 0, stream>>>(x_in, R2);
        else
            transpose16_k<<<dim3(16, 512, 2), tb, 0, stream>>>(XBb, R2, 16384, 512, 8388608, 8388608);
        // S = X^T X per batch: split-K partials
        gemm_nt_k<128><<<dim3(4, 8, 8), 256, 0, stream>>>(R2, R2, 16384, 16384, 512,
            512, 8388608, 2048, nullptr, nullptr, Sp, nullptr);
        sreduce_k<<<2048, 256, 0, stream>>>(Sp, Sbf);
        // T1 = S*Wq, T2 = S*Wk
        gemm_nt_k<64><<<dim3(4, 16), 256, 0, stream>>>(Sbf, WQt + l * 262144, 512, 512, 512,
            BIG, 0, 0, nullptr, nullptr, T1f, nullptr);
        gemm_nt_k<64><<<dim3(4, 16), 256, 0, stream>>>(Sbf, WKt + l * 262144, 512, 512, 512,
            BIG, 0, 0, nullptr, nullptr, T2f, nullptr);
        nrm_k<<<8, 256, 0, stream>>>(Wq + l * 262144, T1f, QNI);
        nrm_k<<<8, 256, 0, stream>>>(Wk + l * 262144, T2f, KNI);
        gsmall_k<<<dim3(8, 2), 256, 0, stream>>>(T2f, Wq + l * 262144, QNI, KNI,
            resc + l * 8, ATT);
        mbuild_k<<<dim3(8, 2), 256, 0, stream>>>(ATT, projW + l * 262144, Mnt);
        // V = x @ Wv
        gemm_nt_k<64><<<dim3(4, 512), 256, 0, stream>>>(XBb, WVt + l * 262144, 512, 512, 512,
            BIG, 0, 0, nullptr, nullptr, nullptr, R3);
        // x += V @ M^T + proj_b
        gemm_nt_k<64><<<dim3(4, 512), 256, 0, stream>>>(R3, Mnt, 512, 512, 512,
            16384, 262144, 0, projB + l * 512, XF, XF, nullptr);
        // positional branch: dwconv3+gelu -> R2, then dwconv3 accumulated into XF
        dwreg_k<3, 16, 4, true, false, false, 512, 512><<<dim3(64, 8, 2), 256, 0, stream>>>(
            R3, posw1 + l * 4608, R2, nullptr);
        dwreg_k<3, 16, 4, false, false, true, 512, 512><<<dim3(64, 8, 2), 256, 0, stream>>>(
            R2, posw2 + l * 4608, nullptr, XF);
        // PreNorm
        ln_k<<<8192, 256, 0, stream>>>(XF, lng + l * 512, lnb + l * 512, XBb);
        // MS-FFN: per-batch slabs, groups merged in PAIRS into Y2 [16384][1024],
        // down-projection as K=1024 GEMMs (halves fp32 XF RMW passes).
        for (int b2 = 0; b2 < 2; b2++) {
            const size_t boff = (size_t)b2 * NPIX * 512;
            // ---- pair 0: g0 (1x1 folded into W2b prescale) + g1 (3x3) ----
            gemm_nt_k<64><<<dim3(4, 256), 256, 0, stream>>>(XBb + boff,
                W1b + l * 1048576 + 0 * 262144, 512, 512, 1024,
                BIG, 0, 0, nullptr, nullptr, nullptr, Y2);            // g0 -> Y2[:,0:512]
            gemm_nt_k<64><<<dim3(4, 256), 256, 0, stream>>>(XBb + boff,
                W1b + l * 1048576 + 1 * 262144, 512, 512, 512,
                BIG, 0, 0, nullptr, nullptr, nullptr, R3s);           // g1 -> R3s
            dwreg_k<3, 16, 4, false, true, false, 512, 1024><<<dim3(64, 8, 1), 256, 0, stream>>>(
                R3s, dw3 + l * 4608, Y2 + 512, nullptr);              // -> Y2[:,512:1024]
            gemm_nt_k<64><<<dim3(4, 256), 256, 0, stream>>>(Y2,
                W2b + l * 1048576 + 0, 1024, 2048, 512,
                BIG, 0, 0, nullptr, XF + boff, XF + boff, nullptr);   // down pair 0
            // ---- pair 1: g2 (5x5) + g3 (7x7) ----
            gemm_nt_k<64><<<dim3(4, 256), 256, 0, stream>>>(XBb + boff,
                W1b + l * 1048576 + 2 * 262144, 512, 512, 512,
                BIG, 0, 0, nullptr, nullptr, nullptr, R3s);           // g2 -> R3s
            dwreg_k<5, 16, 2, false, true, false, 512, 1024><<<dim3(128, 8, 1), 256, 0, stream>>>(
                R3s, dw5 + l * 12800, Y2 + 0, nullptr);               // -> Y2[:,0:512]
            gemm_nt_k<64><<<dim3(4, 256), 256, 0, stream>>>(XBb + boff,
                W1b + l * 1048576 + 3 * 262144, 512, 512, 512,
                BIG, 0, 0, nullptr, nullptr, nullptr, R3s);           // g3 -> R3s
            dwreg_k<7, 32, 2, false, true, false, 512, 1024><<<dim3(128, 4, 1), 256, 0, stream>>>(
                R3s, dw7 + l * 25088, Y2 + 512, nullptr);             // -> Y2[:,512:1024]
            gemm_nt_k<64><<<dim3(4, 256), 256, 0, stream>>>(Y2,
                W2b + l * 1048576 + 1024, 1024, 2048, 512,
                BIG, 0, 0, nullptr, XF + boff, XF + boff, XBb + boff); // down pair 1 (+raw-x bf16)
        }
    }
    // final: XF [b,n,c] -> out [b,c,n]
    transpose_k<<<dim3(16, 512, 2), tb, 0, stream>>>(XF, out, nullptr, 16384, 512, 8388608, 8388608);
}

// Round 6
// 1831.648 us; speedup vs baseline: 1.1012x; 1.0425x over previous
//
#include <hip/hip_runtime.h>
#include <math.h>

typedef unsigned short u16;
typedef short bf16x8 __attribute__((ext_vector_type(8)));
typedef float f32x4 __attribute__((ext_vector_type(4)));
typedef float f32x2 __attribute__((ext_vector_type(2)));

__device__ __forceinline__ float bf2f(u16 h) {
    union { unsigned u; float f; } v; v.u = ((unsigned)h) << 16; return v.f;
}
__device__ __forceinline__ u16 f2bf(float f) {
    union { float f; unsigned u; } v; v.f = f;
    unsigned r = v.u + 0x7fffu + ((v.u >> 16) & 1u);
    return (u16)(r >> 16);
}
__device__ __forceinline__ f32x2 up2(unsigned u) {
    union { unsigned v; float f; } lo, hi;
    lo.v = u << 16; hi.v = u & 0xffff0000u;
    f32x2 r; r.x = lo.f; r.y = hi.f; return r;
}
__device__ __forceinline__ f32x2 unpk(unsigned u) { return up2(u); }
__device__ __forceinline__ f32x4 unpk(uint2 u) {
    f32x2 a = up2(u.x), b = up2(u.y);
    f32x4 r; r.x = a.x; r.y = a.y; r.z = b.x; r.w = b.y; return r;
}
__device__ __forceinline__ unsigned pkbf(f32x2 v) {
    return (unsigned)f2bf(v.x) | ((unsigned)f2bf(v.y) << 16);
}
__device__ __forceinline__ uint2 pkbf(f32x4 v) {
    uint2 r;
    r.x = (unsigned)f2bf(v.x) | ((unsigned)f2bf(v.y) << 16);
    r.y = (unsigned)f2bf(v.z) | ((unsigned)f2bf(v.w) << 16);
    return r;
}
__device__ __forceinline__ float gl(float v) {
    return 0.5f * v * (1.f + erff(v * 0.70710678118654752f));
}

// async global->LDS 16B: LDS dest must be wave-uniform; HW adds lane*16
__device__ __forceinline__ void gload_lds16(const u16* g, u16* l) {
    __builtin_amdgcn_global_load_lds(
        (const __attribute__((address_space(1))) void*)g,
        (__attribute__((address_space(3))) void*)l, 16, 0, 0);
}

template<int N> struct VecT;
template<> struct VecT<2> { typedef f32x2 T; typedef unsigned U; };
template<> struct VecT<4> { typedef f32x4 T; typedef uint2 U; };

#define CH    512
#define NPIX  16384
#define PTOT  32768
#define NHEAD 8

// ---------------- fp32 transpose [R][Cc] -> [Cc][R] per z slab ----------------
__global__ void transpose_k(const float* __restrict__ in, float* outF, u16* outB,
                            int R, int Cc, size_t ibs, size_t obs)
{
    __shared__ float tile[32][33];
    int z = blockIdx.z;
    const float* ip = in + (size_t)z * ibs;
    int c0 = blockIdx.x * 32, r0 = blockIdx.y * 32;
    int tx = threadIdx.x, ty = threadIdx.y;
#pragma unroll
    for (int j = 0; j < 4; j++)
        tile[ty + j * 8][tx] = ip[(size_t)(r0 + ty + j * 8) * Cc + c0 + tx];
    __syncthreads();
#pragma unroll
    for (int j = 0; j < 4; j++) {
        int orow = c0 + ty + j * 8, ocol = r0 + tx;
        float v = tile[tx][ty + j * 8];
        size_t o = (size_t)z * obs + (size_t)orow * R + ocol;
        if (outF) outF[o] = v;
        if (outB) outB[o] = f2bf(v);
    }
}

// ---------------- bf16 transpose [R][Cc] -> [Cc][R] per z slab ----------------
__global__ void transpose16_k(const u16* __restrict__ in, u16* __restrict__ out,
                              int R, int Cc, size_t ibs, size_t obs)
{
    __shared__ u16 tile[32][34];
    int z = blockIdx.z;
    const u16* ip = in + (size_t)z * ibs;
    int c0 = blockIdx.x * 32, r0 = blockIdx.y * 32;
    int tx = threadIdx.x, ty = threadIdx.y;
#pragma unroll
    for (int j = 0; j < 4; j++)
        tile[ty + j * 8][tx] = ip[(size_t)(r0 + ty + j * 8) * Cc + c0 + tx];
    __syncthreads();
#pragma unroll
    for (int j = 0; j < 4; j++)
        out[(size_t)z * obs + (size_t)(c0 + ty + j * 8) * R + r0 + tx] = tile[tx][ty + j * 8];
}

// ---------------- fp32 -> bf16 convert (4 elems/thread) ----------------
__global__ void cvt_bf16_k(const float* __restrict__ in, u16* __restrict__ out)
{
    size_t i = ((size_t)blockIdx.x * 256 + threadIdx.x) * 4;
    float4 v = *(const float4*)&in[i];
    uint2 st;
    st.x = (unsigned)f2bf(v.x) | ((unsigned)f2bf(v.y) << 16);
    st.y = (unsigned)f2bf(v.z) | ((unsigned)f2bf(v.w) << 16);
    *(uint2*)&out[i] = st;
}

// ---------------- w2 convert with group-0 (1+dw1[c]) column prescale ----------
__global__ void cvtw2_k(const float* __restrict__ in, const float* __restrict__ dw1,
                        u16* __restrict__ out)
{
    size_t i = ((size_t)blockIdx.x * 256 + threadIdx.x) * 4;   // over 2*512*2048
    int c = (int)(i & 2047);
    int l = (int)(i >> 20);
    float4 v = *(const float4*)&in[i];
    if (c < 512) {
        v.x *= 1.f + dw1[l * 512 + c];
        v.y *= 1.f + dw1[l * 512 + c + 1];
        v.z *= 1.f + dw1[l * 512 + c + 2];
        v.w *= 1.f + dw1[l * 512 + c + 3];
    }
    uint2 st;
    st.x = (unsigned)f2bf(v.x) | ((unsigned)f2bf(v.y) << 16);
    st.y = (unsigned)f2bf(v.z) | ((unsigned)f2bf(v.w) << 16);
    *(uint2*)&out[i] = st;
}

// ---------------- bf16 NT GEMM: out[i,o] = sum_k A[i,k]*B[o,k] ----------------
// 2-phase pipelined global_load_lds staging, LDS slot-XOR swizzle ->
// conflict-free staging/reads. TM==64 has a vectorized epilogue: acc is
// transposed through a padded LDS tile (two 32-row halves reusing the staging
// LDS) so resid/outF/outB traffic is float4/uint2 coalesced.
template<int TM>
__global__ __launch_bounds__(256) void gemm_nt_k(
    const u16* __restrict__ A, const u16* __restrict__ Bw,
    int K, int ldb, int Nn, int rowsPerBatch, int bStride, int kChunk,
    const float* __restrict__ bias, const float* resid,
    float* outF, u16* outB)
{
    constexpr int MT = TM / 32;          // m-frags per wave
    constexpr int ABUF = TM * 32;        // elems per A buffer
    __shared__ __attribute__((aligned(16))) u16 smem[2 * ABUF + 2 * 128 * 32];
    u16* Asb = smem;                     // [2][ABUF]
    u16* Bsb = smem + 2 * ABUF;          // [2][4096]
    int tid = threadIdx.x;
    int rowBase = blockIdx.y * TM, colBase = blockIdx.x * 128;
    const u16* Bp = Bw + (size_t)(rowBase / rowsPerBatch) * bStride;

    int kb = 0, ke = K;
    float* outFp = outF;
    if (kChunk) {
        kb = blockIdx.z * kChunk; ke = kb + kChunk;
        outFp = outF + (size_t)blockIdx.z * (size_t)gridDim.y * TM * Nn;
    }

    f32x4 acc[MT][4] = {};
    int lane = tid & 63, wave = tid >> 6;
    int wr = wave >> 1, wc = wave & 1;
    int lm = lane & 15, lk = lane >> 4;

    int row0 = tid >> 2;                       // rows 0..63
    int kc   = ((tid ^ (tid >> 3)) & 3) * 8;   // pre-swizzled source k-slot
    int lb0  = (tid & ~63) * 8;                // wave-uniform LDS elem base

    const size_t aR0 = (size_t)(rowBase + row0) * K;
    const size_t bR0 = (size_t)(colBase + row0) * ldb;
    const size_t aR1 = (size_t)(rowBase + 64 + row0) * K;       // TM=128 only
    const size_t bR1 = (size_t)(colBase + 64 + row0) * ldb;

    auto STAGE = [&](int bsel, int k0) {
        gload_lds16(&A [aR0 + k0 + kc], Asb + bsel * ABUF + lb0);
        gload_lds16(&Bp[bR0 + k0 + kc], Bsb + bsel * 4096 + lb0);
        if constexpr (TM == 128)
            gload_lds16(&A [aR1 + k0 + kc], Asb + bsel * ABUF + lb0 + 2048);
        gload_lds16(&Bp[bR1 + k0 + kc], Bsb + bsel * 4096 + lb0 + 2048);
    };

    STAGE(0, kb);
    __syncthreads();                 // tile 0 visible
    int buf = 0;
    const int sl = (lk ^ ((lm >> 1) & 3)) * 8;   // swizzled read slot

    for (int k0 = kb; k0 < ke; k0 += 32) {
        if (k0 + 32 < ke) STAGE(buf ^ 1, k0 + 32);   // prefetch next tile
        const u16* Ab = Asb + buf * ABUF;
        const u16* Bb = Bsb + buf * 4096;
        bf16x8 af[MT], bfr[4];
#pragma unroll
        for (int mt = 0; mt < MT; mt++)
            af[mt] = *(const bf16x8*)&Ab[(wr * (TM / 2) + mt * 16 + lm) * 32 + sl];
#pragma unroll
        for (int nt = 0; nt < 4; nt++)
            bfr[nt] = *(const bf16x8*)&Bb[(wc * 64 + nt * 16 + lm) * 32 + sl];
#pragma unroll
        for (int mt = 0; mt < MT; mt++)
#pragma unroll
            for (int nt = 0; nt < 4; nt++)
                acc[mt][nt] = __builtin_amdgcn_mfma_f32_16x16x32_bf16(
                    af[mt], bfr[nt], acc[mt][nt], 0, 0, 0);
        __syncthreads();             // prefetch landed + all reads of buf done
        buf ^= 1;
    }

    if constexpr (TM == 64) {
        // ---- vectorized epilogue: LDS transpose, two 32-row halves ----
        float* smf = (float*)smem;              // 32 x 132 fp32 = 16896 B
        const int erow = tid >> 5;              // 0..7
        const int ecol = (tid & 31) * 4;        // 0,4,..124
        for (int hf = 0; hf < 2; ++hf) {
            __syncthreads();
            if (wr == hf) {
#pragma unroll
                for (int mt = 0; mt < MT; mt++)
#pragma unroll
                    for (int nt = 0; nt < 4; nt++) {
                        int lr = mt * 16 + lk * 4;
                        int lc = wc * 64 + nt * 16 + lm;
#pragma unroll
                        for (int r = 0; r < 4; r++)
                            smf[(lr + r) * 132 + lc] = acc[mt][nt][r];
                    }
            }
            __syncthreads();
#pragma unroll
            for (int p = 0; p < 4; p++) {
                int lrow = erow + p * 8;                    // 0..31
                int grow = rowBase + hf * 32 + lrow;
                int gcol = colBase + ecol;
                f32x4 v = *(f32x4*)&smf[lrow * 132 + ecol];
                if (bias) {
                    v.x += bias[gcol];     v.y += bias[gcol + 1];
                    v.z += bias[gcol + 2]; v.w += bias[gcol + 3];
                }
                size_t o = (size_t)grow * Nn + gcol;
                if (resid) { f32x4 rv = *(const f32x4*)&resid[o]; v += rv; }
                if (outFp) *(f32x4*)&outFp[o] = v;
                if (outB) { uint2 pk = pkbf(v); *(uint2*)&outB[o] = pk; }
            }
        }
    } else {
#pragma unroll
        for (int mt = 0; mt < MT; mt++)
#pragma unroll
            for (int nt = 0; nt < 4; nt++) {
                int col = colBase + wc * 64 + nt * 16 + lm;
                float bv = bias ? bias[col] : 0.f;
#pragma unroll
                for (int r = 0; r < 4; r++) {
                    int row = rowBase + wr * (TM / 2) + mt * 16 + lk * 4 + r;
                    size_t o = (size_t)row * Nn + col;
                    float v = acc[mt][nt][r] + bv;
                    if (resid) v += resid[o];
                    if (outFp) outFp[o] = v;
                    if (outB) outB[o] = f2bf(v);
                }
            }
    }
}

// ---------------- reduce 8 split-K partials -> bf16 ----------------
__global__ void sreduce_k(const float* __restrict__ Sp, u16* __restrict__ Sbf)
{
    int i = blockIdx.x * 256 + threadIdx.x;
    float s = 0.f;
#pragma unroll
    for (int z = 0; z < 8; z++) s += Sp[(size_t)z * 524288 + i];
    Sbf[i] = f2bf(s);
}

// ---------------- inv l2 norms ----------------
__global__ void nrm_k(const float* __restrict__ w, const float* __restrict__ Tf,
                      float* __restrict__ inv)
{
    int idx = blockIdx.x * 256 + threadIdx.x;   // 0..2047
    int e = idx & 511, b = idx >> 9;
    float s = 0.f;
    for (int c = 0; c < 512; c++)
        s += w[c * 512 + e] * Tf[(size_t)(b * 512 + c) * 512 + e];
    s = fmaxf(s, 0.f);
    inv[b * 512 + e] = 1.f / fmaxf(sqrtf(s), 1e-12f);
}

// ---------------- G[b,h,d,e]=sum_c T2[b,c,h64+d]*Wq[c,h64+e]; scale+softmax ----
__global__ __launch_bounds__(256) void gsmall_k(
    const float* __restrict__ T2f, const float* __restrict__ Wq,
    const float* __restrict__ qinv, const float* __restrict__ kinv,
    const float* __restrict__ resc, float* __restrict__ att)
{
    __shared__ float t2l[64][64], wql[64][64];
    int t = threadIdx.x, h = blockIdx.x, b = blockIdx.y;
    int e = t & 63, g4 = t >> 6;
    float acc[16];
#pragma unroll
    for (int r = 0; r < 16; r++) acc[r] = 0.f;
    for (int c0 = 0; c0 < 512; c0 += 64) {
        __syncthreads();
        for (int i = t; i < 4096; i += 256) {
            int cc = i >> 6, j = i & 63;
            t2l[cc][j] = T2f[(size_t)(b * 512 + c0 + cc) * 512 + h * 64 + j];
            wql[cc][j] = Wq[(size_t)(c0 + cc) * 512 + h * 64 + j];
        }
        __syncthreads();
        for (int cc = 0; cc < 64; cc++) {
            float qv = wql[cc][e];
#pragma unroll
            for (int r = 0; r < 16; r++) acc[r] += t2l[cc][g4 * 16 + r] * qv;
        }
    }
    float qn = qinv[b * 512 + h * 64 + e];
    float rs = resc[h];
    float* ap = att + (size_t)(b * 8 + h) * 4096;
    for (int r = 0; r < 16; r++) {
        int d = g4 * 16 + r;
        float v = acc[r] * kinv[b * 512 + h * 64 + d] * qn * rs;
        float m = v;
        for (int off = 32; off; off >>= 1) m = fmaxf(m, __shfl_xor(m, off));
        float ev = expf(v - m);
        float s = ev;
        for (int off = 32; off; off >>= 1) s += __shfl_xor(s, off);
        ap[d * 64 + e] = ev / s;
    }
}

// ---------------- M[b] fold ----------------
__global__ __launch_bounds__(256) void mbuild_k(const float* __restrict__ attn,
                                                const float* __restrict__ projW,
                                                u16* Mnt)
{
    __shared__ float at[64][64];
    __shared__ float pw[64][64];
    int t = threadIdx.x;
    int h = blockIdx.x, b = blockIdx.y;
    int e = t & 63, g4 = t >> 6;
    const float* ap = attn + (size_t)(b * NHEAD + h) * 4096;
    for (int i = t; i < 4096; i += 256) at[i >> 6][i & 63] = ap[i];
    for (int ot = 0; ot < 8; ot++) {
        __syncthreads();
        for (int i = t; i < 4096; i += 256)
            pw[i >> 6][i & 63] = projW[(size_t)(h * 64 + (i >> 6)) * CH + ot * 64 + (i & 63)];
        __syncthreads();
        float acc[16];
#pragma unroll
        for (int r = 0; r < 16; r++) acc[r] = 0.f;
        for (int dd = 0; dd < 64; dd++) {
            float av = at[dd][e];
#pragma unroll
            for (int r = 0; r < 16; r++) acc[r] += av * pw[dd][g4 * 16 + r];
        }
#pragma unroll
        for (int r = 0; r < 16; r++)
            Mnt[(size_t)b * (CH * CH) + (size_t)(ot * 64 + g4 * 16 + r) * CH + h * 64 + e]
                = f2bf(acc[r]);
        __syncthreads();
    }
}

// ============ register-sliding-window NHWC depthwise conv (pipelined) ============
// SI/SO: input/output channel strides (512 for [n][512] buffers, 2048 for Y2
// column-slot reads/writes). Channels are always 0..511.
template<int KS, int YS, int CPT, bool GELU_F, bool RESID, bool ACC, int SI, int SO>
__global__ __launch_bounds__(256, 1) void dwreg_k(
    const u16* __restrict__ in, const float* __restrict__ w,
    u16* __restrict__ outB, float* __restrict__ outAdd)
{
    constexpr int PAD = KS / 2;
    typedef typename VecT<CPT>::T fv;
    typedef typename VecT<CPT>::U uv;
    const int tid = threadIdx.x;
    const int cbase = (CPT == 4) ? ((tid & 127) * 4) : (tid * 2);
    const int x     = (CPT == 4) ? ((int)blockIdx.x * 2 + (tid >> 7)) : (int)blockIdx.x;
    const int y0 = blockIdx.y * YS;
    const int b  = blockIdx.z;
    const size_t bi = (size_t)b * NPIX * SI + cbase;
    const size_t bo = (size_t)b * NPIX * SO + cbase;

    fv wv[KS * KS];
#pragma unroll
    for (int t = 0; t < KS * KS; t++) {
        fv vv;
        vv.x = w[(cbase + 0) * KS * KS + t];
        vv.y = w[(cbase + 1) * KS * KS + t];
        if constexpr (CPT == 4) {
            vv.z = w[(cbase + 2) * KS * KS + t];
            vv.w = w[(cbase + 3) * KS * KS + t];
        }
        wv[t] = vv;
    }

    fv win[KS][KS];
    uv tmp[KS];

    auto rowload = [&](int t) {
        int yy = y0 - PAD + t;
        bool rv = ((unsigned)yy < 128u);
#pragma unroll
        for (int kx = 0; kx < KS; kx++) {
            int xx = x + kx - PAD;
            uv u = {};
            if (rv && ((unsigned)xx < 128u))
                u = *(const uv*)&in[bi + ((size_t)yy * 128 + xx) * SI];
            tmp[kx] = u;
        }
    };
    auto unpackrow = [&](int slot) {
#pragma unroll
        for (int kx = 0; kx < KS; kx++) win[slot][kx] = unpk(tmp[kx]);
    };

#pragma unroll
    for (int t = 0; t < KS - 1; t++) { rowload(t); unpackrow(t); }
    rowload(KS - 1);

    for (int i0 = 0; i0 < YS; i0 += KS) {
#pragma unroll
        for (int j = 0; j < KS; j++) {
            int i = i0 + j;
            if (i >= YS) break;
            unpackrow((j + KS - 1) % KS);
            if (i < YS - 1) rowload(i + KS);
            fv r = {};
#pragma unroll
            for (int ky = 0; ky < KS; ky++)
#pragma unroll
                for (int kx = 0; kx < KS; kx++)
                    r += win[(j + ky) % KS][kx] * wv[ky * KS + kx];
            if (GELU_F) {
                r.x = gl(r.x); r.y = gl(r.y);
                if constexpr (CPT == 4) { r.z = gl(r.z); r.w = gl(r.w); }
            }
            if (RESID) r += win[(j + PAD) % KS][PAD];
            size_t opos = bo + ((size_t)(y0 + i) * 128 + x) * SO;
            if (ACC) {
                fv* p = (fv*)&outAdd[opos];
                *p = *p + r;
            } else {
                uv pk = pkbf(r);
                *(uv*)&outB[opos] = pk;
            }
        }
    }
}

// ---------------- LayerNorm over c=512 per pixel, bf16 out ----------------
__global__ void ln_k(const float* __restrict__ xf, const float* __restrict__ g,
                     const float* __restrict__ bb, u16* __restrict__ xn)
{
    int t = threadIdx.x, lane = t & 63, wv = t >> 6;
    size_t pix = (size_t)blockIdx.x * 4 + wv;
    const float* row = xf + pix * CH;
    float4 a = *(const float4*)&row[lane * 8];
    float4 c = *(const float4*)&row[lane * 8 + 4];
    float s = a.x + a.y + a.z + a.w + c.x + c.y + c.z + c.w;
    float sq = a.x * a.x + a.y * a.y + a.z * a.z + a.w * a.w
             + c.x * c.x + c.y * c.y + c.z * c.z + c.w * c.w;
    for (int off = 32; off; off >>= 1) {
        s  += __shfl_xor(s, off);
        sq += __shfl_xor(sq, off);
    }
    float mu = s * (1.f / 512.f);
    float var = fmaxf(sq * (1.f / 512.f) - mu * mu, 0.f);
    float inv = rsqrtf(var + 1e-5f);
    float vals[8] = {a.x, a.y, a.z, a.w, c.x, c.y, c.z, c.w};
    unsigned o[4];
#pragma unroll
    for (int j = 0; j < 4; j++) {
        int cix = lane * 8 + j * 2;
        float v0 = (vals[j * 2] - mu) * inv * g[cix] + bb[cix];
        float v1 = (vals[j * 2 + 1] - mu) * inv * g[cix + 1] + bb[cix + 1];
        o[j] = (unsigned)f2bf(v0) | ((unsigned)f2bf(v1) << 16);
    }
    *(uint4*)&xn[pix * CH + lane * 8] = make_uint4(o[0], o[1], o[2], o[3]);
}

// =====================================================================
extern "C" void kernel_launch(void* const* d_in, const int* in_sizes, int n_in,
                              void* d_out, int out_size, void* d_ws, size_t ws_size,
                              hipStream_t stream)
{
    (void)in_sizes; (void)n_in; (void)out_size; (void)ws_size;
    const float* x_in  = (const float*)d_in[0];
    const float* Wq    = (const float*)d_in[1];
    const float* Wk    = (const float*)d_in[2];
    const float* Wv    = (const float*)d_in[3];
    const float* resc  = (const float*)d_in[4];
    const float* projW = (const float*)d_in[5];
    const float* projB = (const float*)d_in[6];
    const float* posw1 = (const float*)d_in[7];
    const float* posw2 = (const float*)d_in[8];
    const float* lng   = (const float*)d_in[9];
    const float* lnb   = (const float*)d_in[10];
    const float* w1    = (const float*)d_in[11];
    const float* dw1   = (const float*)d_in[12];
    const float* dw3   = (const float*)d_in[13];
    const float* dw5   = (const float*)d_in[14];
    const float* dw7   = (const float*)d_in[15];
    const float* w2    = (const float*)d_in[16];
    float* out = (float*)d_out;
    char* ws = (char*)d_ws;

    // ---- d_ws layout (~119 MB) ----
    float* XF  = (float*)(ws + 0);               // 64 MB fp32 state [b,n,c]
    u16*   XBb = (u16*)  (ws + 67108864ull);     // 32 MB bf16 x / xn [b,n,c]
    u16*   WQt = (u16*)  (ws + 100663296ull);    // 1 MB [2][512][512]
    u16*   WKt = (u16*)  (ws + 101711872ull);    // 1 MB
    u16*   WVt = (u16*)  (ws + 102760448ull);    // 1 MB
    u16*   W1b = (u16*)  (ws + 103809024ull);    // 4 MB [2][2048][512]
    u16*   W2b = (u16*)  (ws + 108003328ull);    // 4 MB [2][512][2048]
    u16*   Mnt = (u16*)  (ws + 112197632ull);    // 1 MB [2][512][512]
    u16*   Sbf = (u16*)  (ws + 113246208ull);    // 1 MB [2][512][512]
    float* T1f = (float*)(ws + 114294784ull);    // 2 MB [2][512][512]
    float* T2f = (float*)(ws + 116391936ull);    // 2 MB
    float* QNI = (float*)(ws + 118489088ull);    // 4 KB [2][512]
    float* KNI = (float*)(ws + 118493184ull);    // 4 KB
    float* ATT = (float*)(ws + 118497280ull);    // 256 KB [2][8][64][64]

    // ---- d_out used as scratch until the final transpose ----
    u16*   R2  = (u16*)d_out;                    // 32 MB (attn phase)
    u16*   R3  = (u16*)d_out + 16777216;         // 32 MB (attn phase)
    float* Sp  = (float*)((char*)d_out + 33554432ull); // 16 MB split-K partials
    u16*   Y2  = (u16*)d_out;                    // FFN: [16384][2048] bf16 (64 MB/batch slab)

    const int BIG = 1 << 30;
    dim3 tb(32, 8);

    // prep
    transpose_k<<<dim3(512, 16, 2), tb, 0, stream>>>(x_in, XF, XBb, 512, 16384, 8388608, 8388608);
    transpose_k<<<dim3(16, 16, 2), tb, 0, stream>>>(Wq, nullptr, WQt, 512, 512, 262144, 262144);
    transpose_k<<<dim3(16, 16, 2), tb, 0, stream>>>(Wk, nullptr, WKt, 512, 512, 262144, 262144);
    transpose_k<<<dim3(16, 16, 2), tb, 0, stream>>>(Wv, nullptr, WVt, 512, 512, 262144, 262144);
    cvt_bf16_k<<<2048, 256, 0, stream>>>(w1, W1b);
    cvtw2_k<<<2048, 256, 0, stream>>>(w2, dw1, W2b);

    for (int l = 0; l < 2; l++) {
        // XT (bf16 [b][c][n]) into R2
        if (l == 0)
            cvt_bf16_k<<<16384, 256, 0, stream>>>(x_in, R2);
        else
            transpose16_k<<<dim3(16, 512, 2), tb, 0, stream>>>(XBb, R2, 16384, 512, 8388608, 8388608);
        // S = X^T X per batch: split-K partials
        gemm_nt_k<128><<<dim3(4, 8, 8), 256, 0, stream>>>(R2, R2, 16384, 16384, 512,
            512, 8388608, 2048, nullptr, nullptr, Sp, nullptr);
        sreduce_k<<<2048, 256, 0, stream>>>(Sp, Sbf);
        // T1 = S*Wq, T2 = S*Wk
        gemm_nt_k<64><<<dim3(4, 16), 256, 0, stream>>>(Sbf, WQt + l * 262144, 512, 512, 512,
            BIG, 0, 0, nullptr, nullptr, T1f, nullptr);
        gemm_nt_k<64><<<dim3(4, 16), 256, 0, stream>>>(Sbf, WKt + l * 262144, 512, 512, 512,
            BIG, 0, 0, nullptr, nullptr, T2f, nullptr);
        nrm_k<<<8, 256, 0, stream>>>(Wq + l * 262144, T1f, QNI);
        nrm_k<<<8, 256, 0, stream>>>(Wk + l * 262144, T2f, KNI);
        gsmall_k<<<dim3(8, 2), 256, 0, stream>>>(T2f, Wq + l * 262144, QNI, KNI,
            resc + l * 8, ATT);
        mbuild_k<<<dim3(8, 2), 256, 0, stream>>>(ATT, projW + l * 262144, Mnt);
        // V = x @ Wv
        gemm_nt_k<64><<<dim3(4, 512), 256, 0, stream>>>(XBb, WVt + l * 262144, 512, 512, 512,
            BIG, 0, 0, nullptr, nullptr, nullptr, R3);
        // x += V @ M^T + proj_b
        gemm_nt_k<64><<<dim3(4, 512), 256, 0, stream>>>(R3, Mnt, 512, 512, 512,
            16384, 262144, 0, projB + l * 512, XF, XF, nullptr);
        // positional branch: dwconv3+gelu -> R2, then dwconv3 accumulated into XF
        dwreg_k<3, 16, 4, true, false, false, 512, 512><<<dim3(64, 8, 2), 256, 0, stream>>>(
            R3, posw1 + l * 4608, R2, nullptr);
        dwreg_k<3, 16, 4, false, false, true, 512, 512><<<dim3(64, 8, 2), 256, 0, stream>>>(
            R2, posw2 + l * 4608, nullptr, XF);
        // PreNorm
        ln_k<<<8192, 256, 0, stream>>>(XF, lng + l * 512, lnb + l * 512, XBb);
        // MS-FFN: per-batch slabs. Y2 [16384][2048] with k-column order
        // g0|g1|g2|g3 matching W2b. Single temp slot = cols 0-511, time-
        // multiplexed (stream order makes reuse race-free); g0 lands there
        // last. ONE K=2048 down-GEMM per batch (one XF RMW pass instead of 2).
        for (int b2 = 0; b2 < 2; b2++) {
            const size_t boff = (size_t)b2 * NPIX * 512;
            const u16* w1l = W1b + l * 1048576;
            // up g3 -> temp slot, conv7 -> final cols 1536-2047
            gemm_nt_k<64><<<dim3(4, 256), 256, 0, stream>>>(XBb + boff,
                w1l + 3 * 262144, 512, 512, 2048,
                BIG, 0, 0, nullptr, nullptr, nullptr, Y2);
            dwreg_k<7, 32, 2, false, true, false, 2048, 2048><<<dim3(128, 4, 1), 256, 0, stream>>>(
                Y2, dw7 + l * 25088, Y2 + 1536, nullptr);
            // up g1 -> temp slot, conv3 -> final cols 512-1023
            gemm_nt_k<64><<<dim3(4, 256), 256, 0, stream>>>(XBb + boff,
                w1l + 1 * 262144, 512, 512, 2048,
                BIG, 0, 0, nullptr, nullptr, nullptr, Y2);
            dwreg_k<3, 16, 4, false, true, false, 2048, 2048><<<dim3(64, 8, 1), 256, 0, stream>>>(
                Y2, dw3 + l * 4608, Y2 + 512, nullptr);
            // up g2 -> temp slot, conv5 -> final cols 1024-1535
            gemm_nt_k<64><<<dim3(4, 256), 256, 0, stream>>>(XBb + boff,
                w1l + 2 * 262144, 512, 512, 2048,
                BIG, 0, 0, nullptr, nullptr, nullptr, Y2);
            dwreg_k<5, 16, 2, false, true, false, 2048, 2048><<<dim3(128, 8, 1), 256, 0, stream>>>(
                Y2, dw5 + l * 12800, Y2 + 1024, nullptr);
            // up g0 -> final cols 0-511 (1x1 dw folded into W2b prescale)
            gemm_nt_k<64><<<dim3(4, 256), 256, 0, stream>>>(XBb + boff,
                w1l + 0 * 262144, 512, 512, 2048,
                BIG, 0, 0, nullptr, nullptr, nullptr, Y2);
            // single K=2048 down-GEMM: XF += Y2 @ W2b^T, also emit bf16 x
            gemm_nt_k<64><<<dim3(4, 256), 256, 0, stream>>>(Y2,
                W2b + l * 1048576, 2048, 2048, 512,
                BIG, 0, 0, nullptr, XF + boff, XF + boff, XBb + boff);
        }
    }
    // final: XF [b,n,c] -> out [b,c,n]
    transpose_k<<<dim3(16, 512, 2), tb, 0, stream>>>(XF, out, nullptr, 16384, 512, 8388608, 8388608);
}

// Round 7
// 1820.692 us; speedup vs baseline: 1.1078x; 1.0060x over previous
//
#include <hip/hip_runtime.h>
#include <math.h>

typedef unsigned short u16;
typedef short bf16x8 __attribute__((ext_vector_type(8)));
typedef float f32x4 __attribute__((ext_vector_type(4)));
typedef float f32x2 __attribute__((ext_vector_type(2)));

__device__ __forceinline__ float bf2f(u16 h) {
    union { unsigned u; float f; } v; v.u = ((unsigned)h) << 16; return v.f;
}
__device__ __forceinline__ u16 f2bf(float f) {
    union { float f; unsigned u; } v; v.f = f;
    unsigned r = v.u + 0x7fffu + ((v.u >> 16) & 1u);
    return (u16)(r >> 16);
}
__device__ __forceinline__ f32x2 up2(unsigned u) {
    union { unsigned v; float f; } lo, hi;
    lo.v = u << 16; hi.v = u & 0xffff0000u;
    f32x2 r; r.x = lo.f; r.y = hi.f; return r;
}
__device__ __forceinline__ f32x2 unpk(unsigned u) { return up2(u); }
__device__ __forceinline__ f32x4 unpk(uint2 u) {
    f32x2 a = up2(u.x), b = up2(u.y);
    f32x4 r; r.x = a.x; r.y = a.y; r.z = b.x; r.w = b.y; return r;
}
__device__ __forceinline__ unsigned pkbf(f32x2 v) {
    return (unsigned)f2bf(v.x) | ((unsigned)f2bf(v.y) << 16);
}
__device__ __forceinline__ uint2 pkbf(f32x4 v) {
    uint2 r;
    r.x = (unsigned)f2bf(v.x) | ((unsigned)f2bf(v.y) << 16);
    r.y = (unsigned)f2bf(v.z) | ((unsigned)f2bf(v.w) << 16);
    return r;
}
__device__ __forceinline__ float gl(float v) {
    return 0.5f * v * (1.f + erff(v * 0.70710678118654752f));
}

// async global->LDS 16B: LDS dest must be wave-uniform; HW adds lane*16
__device__ __forceinline__ void gload_lds16(const u16* g, u16* l) {
    __builtin_amdgcn_global_load_lds(
        (const __attribute__((address_space(1))) void*)g,
        (__attribute__((address_space(3))) void*)l, 16, 0, 0);
}

template<int N> struct VecT;
template<> struct VecT<2> { typedef f32x2 T; typedef unsigned U; };
template<> struct VecT<4> { typedef f32x4 T; typedef uint2 U; };

#define CH    512
#define NPIX  16384
#define PTOT  32768
#define NHEAD 8

// ---------------- fp32 transpose [R][Cc] -> [Cc][R] per z slab ----------------
__global__ void transpose_k(const float* __restrict__ in, float* outF, u16* outB,
                            int R, int Cc, size_t ibs, size_t obs)
{
    __shared__ float tile[32][33];
    int z = blockIdx.z;
    const float* ip = in + (size_t)z * ibs;
    int c0 = blockIdx.x * 32, r0 = blockIdx.y * 32;
    int tx = threadIdx.x, ty = threadIdx.y;
#pragma unroll
    for (int j = 0; j < 4; j++)
        tile[ty + j * 8][tx] = ip[(size_t)(r0 + ty + j * 8) * Cc + c0 + tx];
    __syncthreads();
#pragma unroll
    for (int j = 0; j < 4; j++) {
        int orow = c0 + ty + j * 8, ocol = r0 + tx;
        float v = tile[tx][ty + j * 8];
        size_t o = (size_t)z * obs + (size_t)orow * R + ocol;
        if (outF) outF[o] = v;
        if (outB) outB[o] = f2bf(v);
    }
}

// ---------------- bf16 transpose [R][Cc] -> [Cc][R] per z slab ----------------
__global__ void transpose16_k(const u16* __restrict__ in, u16* __restrict__ out,
                              int R, int Cc, size_t ibs, size_t obs)
{
    __shared__ u16 tile[32][34];
    int z = blockIdx.z;
    const u16* ip = in + (size_t)z * ibs;
    int c0 = blockIdx.x * 32, r0 = blockIdx.y * 32;
    int tx = threadIdx.x, ty = threadIdx.y;
#pragma unroll
    for (int j = 0; j < 4; j++)
        tile[ty + j * 8][tx] = ip[(size_t)(r0 + ty + j * 8) * Cc + c0 + tx];
    __syncthreads();
#pragma unroll
    for (int j = 0; j < 4; j++)
        out[(size_t)z * obs + (size_t)(c0 + ty + j * 8) * R + r0 + tx] = tile[tx][ty + j * 8];
}

// ---------------- fp32 -> bf16 convert (4 elems/thread) ----------------
__global__ void cvt_bf16_k(const float* __restrict__ in, u16* __restrict__ out)
{
    size_t i = ((size_t)blockIdx.x * 256 + threadIdx.x) * 4;
    float4 v = *(const float4*)&in[i];
    uint2 st;
    st.x = (unsigned)f2bf(v.x) | ((unsigned)f2bf(v.y) << 16);
    st.y = (unsigned)f2bf(v.z) | ((unsigned)f2bf(v.w) << 16);
    *(uint2*)&out[i] = st;
}

// ---------------- w2 convert with group-0 (1+dw1[c]) column prescale ----------
__global__ void cvtw2_k(const float* __restrict__ in, const float* __restrict__ dw1,
                        u16* __restrict__ out)
{
    size_t i = ((size_t)blockIdx.x * 256 + threadIdx.x) * 4;   // over 2*512*2048
    int c = (int)(i & 2047);
    int l = (int)(i >> 20);
    float4 v = *(const float4*)&in[i];
    if (c < 512) {
        v.x *= 1.f + dw1[l * 512 + c];
        v.y *= 1.f + dw1[l * 512 + c + 1];
        v.z *= 1.f + dw1[l * 512 + c + 2];
        v.w *= 1.f + dw1[l * 512 + c + 3];
    }
    uint2 st;
    st.x = (unsigned)f2bf(v.x) | ((unsigned)f2bf(v.y) << 16);
    st.y = (unsigned)f2bf(v.z) | ((unsigned)f2bf(v.w) << 16);
    *(uint2*)&out[i] = st;
}

// ---------------- bf16 NT GEMM: out[i,o] = sum_k A[i,k]*B[o,k] ----------------
// 2-phase pipelined global_load_lds staging, LDS slot-XOR swizzle ->
// conflict-free staging/reads. XCD-aware bijective block swizzle: the 4
// col-blocks sharing one A row-panel are co-located on ONE XCD (each XCD owns
// a contiguous work-id chunk), so A panels are fetched into L2 once instead of
// 4x (measured 51 MB/dispatch HBM over-fetch on the K=2048 down-GEMMs).
// TM==64 has a vectorized epilogue (LDS transpose -> float4/uint2 traffic).
template<int TM>
__global__ __launch_bounds__(256) void gemm_nt_k(
    const u16* __restrict__ A, const u16* __restrict__ Bw,
    int K, int ldb, int Nn, int rowsPerBatch, int bStride, int kChunk,
    const float* __restrict__ bias, const float* resid,
    float* outF, u16* outB)
{
    constexpr int MT = TM / 32;          // m-frags per wave
    constexpr int ABUF = TM * 32;        // elems per A buffer
    __shared__ __attribute__((aligned(16))) u16 smem[2 * ABUF + 2 * 128 * 32];
    u16* Asb = smem;                     // [2][ABUF]
    u16* Bsb = smem + 2 * ABUF;          // [2][4096]
    int tid = threadIdx.x;

    // ---- XCD-aware bijective swizzle over the (x,y) plane ----
    int gx = gridDim.x;
    int nwg = gx * gridDim.y;
    int lin = blockIdx.y * gx + blockIdx.x;
    int swz = lin;
    if ((nwg & 7) == 0) swz = (lin & 7) * (nwg >> 3) + (lin >> 3);
    int bx = swz % gx, by = swz / gx;

    int rowBase = by * TM, colBase = bx * 128;
    const u16* Bp = Bw + (size_t)(rowBase / rowsPerBatch) * bStride;

    int kb = 0, ke = K;
    float* outFp = outF;
    if (kChunk) {
        kb = blockIdx.z * kChunk; ke = kb + kChunk;
        outFp = outF + (size_t)blockIdx.z * (size_t)gridDim.y * TM * Nn;
    }

    f32x4 acc[MT][4] = {};
    int lane = tid & 63, wave = tid >> 6;
    int wr = wave >> 1, wc = wave & 1;
    int lm = lane & 15, lk = lane >> 4;

    int row0 = tid >> 2;                       // rows 0..63
    int kc   = ((tid ^ (tid >> 3)) & 3) * 8;   // pre-swizzled source k-slot
    int lb0  = (tid & ~63) * 8;                // wave-uniform LDS elem base

    const size_t aR0 = (size_t)(rowBase + row0) * K;
    const size_t bR0 = (size_t)(colBase + row0) * ldb;
    const size_t aR1 = (size_t)(rowBase + 64 + row0) * K;       // TM=128 only
    const size_t bR1 = (size_t)(colBase + 64 + row0) * ldb;

    auto STAGE = [&](int bsel, int k0) {
        gload_lds16(&A [aR0 + k0 + kc], Asb + bsel * ABUF + lb0);
        gload_lds16(&Bp[bR0 + k0 + kc], Bsb + bsel * 4096 + lb0);
        if constexpr (TM == 128)
            gload_lds16(&A [aR1 + k0 + kc], Asb + bsel * ABUF + lb0 + 2048);
        gload_lds16(&Bp[bR1 + k0 + kc], Bsb + bsel * 4096 + lb0 + 2048);
    };

    STAGE(0, kb);
    __syncthreads();                 // tile 0 visible
    int buf = 0;
    const int sl = (lk ^ ((lm >> 1) & 3)) * 8;   // swizzled read slot

    for (int k0 = kb; k0 < ke; k0 += 32) {
        if (k0 + 32 < ke) STAGE(buf ^ 1, k0 + 32);   // prefetch next tile
        const u16* Ab = Asb + buf * ABUF;
        const u16* Bb = Bsb + buf * 4096;
        bf16x8 af[MT], bfr[4];
#pragma unroll
        for (int mt = 0; mt < MT; mt++)
            af[mt] = *(const bf16x8*)&Ab[(wr * (TM / 2) + mt * 16 + lm) * 32 + sl];
#pragma unroll
        for (int nt = 0; nt < 4; nt++)
            bfr[nt] = *(const bf16x8*)&Bb[(wc * 64 + nt * 16 + lm) * 32 + sl];
#pragma unroll
        for (int mt = 0; mt < MT; mt++)
#pragma unroll
            for (int nt = 0; nt < 4; nt++)
                acc[mt][nt] = __builtin_amdgcn_mfma_f32_16x16x32_bf16(
                    af[mt], bfr[nt], acc[mt][nt], 0, 0, 0);
        __syncthreads();             // prefetch landed + all reads of buf done
        buf ^= 1;
    }

    if constexpr (TM == 64) {
        // ---- vectorized epilogue: LDS transpose, two 32-row halves ----
        float* smf = (float*)smem;              // 32 x 132 fp32 = 16896 B
        const int erow = tid >> 5;              // 0..7
        const int ecol = (tid & 31) * 4;        // 0,4,..124
        for (int hf = 0; hf < 2; ++hf) {
            __syncthreads();
            if (wr == hf) {
#pragma unroll
                for (int mt = 0; mt < MT; mt++)
#pragma unroll
                    for (int nt = 0; nt < 4; nt++) {
                        int lr = mt * 16 + lk * 4;
                        int lc = wc * 64 + nt * 16 + lm;
#pragma unroll
                        for (int r = 0; r < 4; r++)
                            smf[(lr + r) * 132 + lc] = acc[mt][nt][r];
                    }
            }
            __syncthreads();
#pragma unroll
            for (int p = 0; p < 4; p++) {
                int lrow = erow + p * 8;                    // 0..31
                int grow = rowBase + hf * 32 + lrow;
                int gcol = colBase + ecol;
                f32x4 v = *(f32x4*)&smf[lrow * 132 + ecol];
                if (bias) {
                    v.x += bias[gcol];     v.y += bias[gcol + 1];
                    v.z += bias[gcol + 2]; v.w += bias[gcol + 3];
                }
                size_t o = (size_t)grow * Nn + gcol;
                if (resid) { f32x4 rv = *(const f32x4*)&resid[o]; v += rv; }
                if (outFp) *(f32x4*)&outFp[o] = v;
                if (outB) { uint2 pk = pkbf(v); *(uint2*)&outB[o] = pk; }
            }
        }
    } else {
#pragma unroll
        for (int mt = 0; mt < MT; mt++)
#pragma unroll
            for (int nt = 0; nt < 4; nt++) {
                int col = colBase + wc * 64 + nt * 16 + lm;
                float bv = bias ? bias[col] : 0.f;
#pragma unroll
                for (int r = 0; r < 4; r++) {
                    int row = rowBase + wr * (TM / 2) + mt * 16 + lk * 4 + r;
                    size_t o = (size_t)row * Nn + col;
                    float v = acc[mt][nt][r] + bv;
                    if (resid) v += resid[o];
                    if (outFp) outFp[o] = v;
                    if (outB) outB[o] = f2bf(v);
                }
            }
    }
}

// ---------------- reduce 8 split-K partials -> bf16 ----------------
__global__ void sreduce_k(const float* __restrict__ Sp, u16* __restrict__ Sbf)
{
    int i = blockIdx.x * 256 + threadIdx.x;
    float s = 0.f;
#pragma unroll
    for (int z = 0; z < 8; z++) s += Sp[(size_t)z * 524288 + i];
    Sbf[i] = f2bf(s);
}

// ---------------- inv l2 norms ----------------
__global__ void nrm_k(const float* __restrict__ w, const float* __restrict__ Tf,
                      float* __restrict__ inv)
{
    int idx = blockIdx.x * 256 + threadIdx.x;   // 0..2047
    int e = idx & 511, b = idx >> 9;
    float s = 0.f;
    for (int c = 0; c < 512; c++)
        s += w[c * 512 + e] * Tf[(size_t)(b * 512 + c) * 512 + e];
    s = fmaxf(s, 0.f);
    inv[b * 512 + e] = 1.f / fmaxf(sqrtf(s), 1e-12f);
}

// ---------------- G[b,h,d,e]=sum_c T2[b,c,h64+d]*Wq[c,h64+e]; scale+softmax ----
__global__ __launch_bounds__(256) void gsmall_k(
    const float* __restrict__ T2f, const float* __restrict__ Wq,
    const float* __restrict__ qinv, const float* __restrict__ kinv,
    const float* __restrict__ resc, float* __restrict__ att)
{
    __shared__ float t2l[64][64], wql[64][64];
    int t = threadIdx.x, h = blockIdx.x, b = blockIdx.y;
    int e = t & 63, g4 = t >> 6;
    float acc[16];
#pragma unroll
    for (int r = 0; r < 16; r++) acc[r] = 0.f;
    for (int c0 = 0; c0 < 512; c0 += 64) {
        __syncthreads();
        for (int i = t; i < 4096; i += 256) {
            int cc = i >> 6, j = i & 63;
            t2l[cc][j] = T2f[(size_t)(b * 512 + c0 + cc) * 512 + h * 64 + j];
            wql[cc][j] = Wq[(size_t)(c0 + cc) * 512 + h * 64 + j];
        }
        __syncthreads();
        for (int cc = 0; cc < 64; cc++) {
            float qv = wql[cc][e];
#pragma unroll
            for (int r = 0; r < 16; r++) acc[r] += t2l[cc][g4 * 16 + r] * qv;
        }
    }
    float qn = qinv[b * 512 + h * 64 + e];
    float rs = resc[h];
    float* ap = att + (size_t)(b * 8 + h) * 4096;
    for (int r = 0; r < 16; r++) {
        int d = g4 * 16 + r;
        float v = acc[r] * kinv[b * 512 + h * 64 + d] * qn * rs;
        float m = v;
        for (int off = 32; off; off >>= 1) m = fmaxf(m, __shfl_xor(m, off));
        float ev = expf(v - m);
        float s = ev;
        for (int off = 32; off; off >>= 1) s += __shfl_xor(s, off);
        ap[d * 64 + e] = ev / s;
    }
}

// ---------------- M[b] fold ----------------
__global__ __launch_bounds__(256) void mbuild_k(const float* __restrict__ attn,
                                                const float* __restrict__ projW,
                                                u16* Mnt)
{
    __shared__ float at[64][64];
    __shared__ float pw[64][64];
    int t = threadIdx.x;
    int h = blockIdx.x, b = blockIdx.y;
    int e = t & 63, g4 = t >> 6;
    const float* ap = attn + (size_t)(b * NHEAD + h) * 4096;
    for (int i = t; i < 4096; i += 256) at[i >> 6][i & 63] = ap[i];
    for (int ot = 0; ot < 8; ot++) {
        __syncthreads();
        for (int i = t; i < 4096; i += 256)
            pw[i >> 6][i & 63] = projW[(size_t)(h * 64 + (i >> 6)) * CH + ot * 64 + (i & 63)];
        __syncthreads();
        float acc[16];
#pragma unroll
        for (int r = 0; r < 16; r++) acc[r] = 0.f;
        for (int dd = 0; dd < 64; dd++) {
            float av = at[dd][e];
#pragma unroll
            for (int r = 0; r < 16; r++) acc[r] += av * pw[dd][g4 * 16 + r];
        }
#pragma unroll
        for (int r = 0; r < 16; r++)
            Mnt[(size_t)b * (CH * CH) + (size_t)(ot * 64 + g4 * 16 + r) * CH + h * 64 + e]
                = f2bf(acc[r]);
        __syncthreads();
    }
}

// ============ register-sliding-window NHWC depthwise conv (pipelined) ============
// SI/SO: input/output channel strides (512 for [n][512] buffers, 2048 for Y2
// column-slot reads/writes). Channels are always 0..511.
template<int KS, int YS, int CPT, bool GELU_F, bool RESID, bool ACC, int SI, int SO>
__global__ __launch_bounds__(256, 1) void dwreg_k(
    const u16* __restrict__ in, const float* __restrict__ w,
    u16* __restrict__ outB, float* __restrict__ outAdd)
{
    constexpr int PAD = KS / 2;
    typedef typename VecT<CPT>::T fv;
    typedef typename VecT<CPT>::U uv;
    const int tid = threadIdx.x;
    const int cbase = (CPT == 4) ? ((tid & 127) * 4) : (tid * 2);
    const int x     = (CPT == 4) ? ((int)blockIdx.x * 2 + (tid >> 7)) : (int)blockIdx.x;
    const int y0 = blockIdx.y * YS;
    const int b  = blockIdx.z;
    const size_t bi = (size_t)b * NPIX * SI + cbase;
    const size_t bo = (size_t)b * NPIX * SO + cbase;

    fv wv[KS * KS];
#pragma unroll
    for (int t = 0; t < KS * KS; t++) {
        fv vv;
        vv.x = w[(cbase + 0) * KS * KS + t];
        vv.y = w[(cbase + 1) * KS * KS + t];
        if constexpr (CPT == 4) {
            vv.z = w[(cbase + 2) * KS * KS + t];
            vv.w = w[(cbase + 3) * KS * KS + t];
        }
        wv[t] = vv;
    }

    fv win[KS][KS];
    uv tmp[KS];

    auto rowload = [&](int t) {
        int yy = y0 - PAD + t;
        bool rv = ((unsigned)yy < 128u);
#pragma unroll
        for (int kx = 0; kx < KS; kx++) {
            int xx = x + kx - PAD;
            uv u = {};
            if (rv && ((unsigned)xx < 128u))
                u = *(const uv*)&in[bi + ((size_t)yy * 128 + xx) * SI];
            tmp[kx] = u;
        }
    };
    auto unpackrow = [&](int slot) {
#pragma unroll
        for (int kx = 0; kx < KS; kx++) win[slot][kx] = unpk(tmp[kx]);
    };

#pragma unroll
    for (int t = 0; t < KS - 1; t++) { rowload(t); unpackrow(t); }
    rowload(KS - 1);

    for (int i0 = 0; i0 < YS; i0 += KS) {
#pragma unroll
        for (int j = 0; j < KS; j++) {
            int i = i0 + j;
            if (i >= YS) break;
            unpackrow((j + KS - 1) % KS);
            if (i < YS - 1) rowload(i + KS);
            fv r = {};
#pragma unroll
            for (int ky = 0; ky < KS; ky++)
#pragma unroll
                for (int kx = 0; kx < KS; kx++)
                    r += win[(j + ky) % KS][kx] * wv[ky * KS + kx];
            if (GELU_F) {
                r.x = gl(r.x); r.y = gl(r.y);
                if constexpr (CPT == 4) { r.z = gl(r.z); r.w = gl(r.w); }
            }
            if (RESID) r += win[(j + PAD) % KS][PAD];
            size_t opos = bo + ((size_t)(y0 + i) * 128 + x) * SO;
            if (ACC) {
                fv* p = (fv*)&outAdd[opos];
                *p = *p + r;
            } else {
                uv pk = pkbf(r);
                *(uv*)&outB[opos] = pk;
            }
        }
    }
}

// ---------------- LayerNorm over c=512 per pixel, bf16 out ----------------
__global__ void ln_k(const float* __restrict__ xf, const float* __restrict__ g,
                     const float* __restrict__ bb, u16* __restrict__ xn)
{
    int t = threadIdx.x, lane = t & 63, wv = t >> 6;
    size_t pix = (size_t)blockIdx.x * 4 + wv;
    const float* row = xf + pix * CH;
    float4 a = *(const float4*)&row[lane * 8];
    float4 c = *(const float4*)&row[lane * 8 + 4];
    float s = a.x + a.y + a.z + a.w + c.x + c.y + c.z + c.w;
    float sq = a.x * a.x + a.y * a.y + a.z * a.z + a.w * a.w
             + c.x * c.x + c.y * c.y + c.z * c.z + c.w * c.w;
    for (int off = 32; off; off >>= 1) {
        s  += __shfl_xor(s, off);
        sq += __shfl_xor(sq, off);
    }
    float mu = s * (1.f / 512.f);
    float var = fmaxf(sq * (1.f / 512.f) - mu * mu, 0.f);
    float inv = rsqrtf(var + 1e-5f);
    float vals[8] = {a.x, a.y, a.z, a.w, c.x, c.y, c.z, c.w};
    unsigned o[4];
#pragma unroll
    for (int j = 0; j < 4; j++) {
        int cix = lane * 8 + j * 2;
        float v0 = (vals[j * 2] - mu) * inv * g[cix] + bb[cix];
        float v1 = (vals[j * 2 + 1] - mu) * inv * g[cix + 1] + bb[cix + 1];
        o[j] = (unsigned)f2bf(v0) | ((unsigned)f2bf(v1) << 16);
    }
    *(uint4*)&xn[pix * CH + lane * 8] = make_uint4(o[0], o[1], o[2], o[3]);
}

// =====================================================================
extern "C" void kernel_launch(void* const* d_in, const int* in_sizes, int n_in,
                              void* d_out, int out_size, void* d_ws, size_t ws_size,
                              hipStream_t stream)
{
    (void)in_sizes; (void)n_in; (void)out_size; (void)ws_size;
    const float* x_in  = (const float*)d_in[0];
    const float* Wq    = (const float*)d_in[1];
    const float* Wk    = (const float*)d_in[2];
    const float* Wv    = (const float*)d_in[3];
    const float* resc  = (const float*)d_in[4];
    const float* projW = (const float*)d_in[5];
    const float* projB = (const float*)d_in[6];
    const float* posw1 = (const float*)d_in[7];
    const float* posw2 = (const float*)d_in[8];
    const float* lng   = (const float*)d_in[9];
    const float* lnb   = (const float*)d_in[10];
    const float* w1    = (const float*)d_in[11];
    const float* dw1   = (const float*)d_in[12];
    const float* dw3   = (const float*)d_in[13];
    const float* dw5   = (const float*)d_in[14];
    const float* dw7   = (const float*)d_in[15];
    const float* w2    = (const float*)d_in[16];
    float* out = (float*)d_out;
    char* ws = (char*)d_ws;

    // ---- d_ws layout (~119 MB) ----
    float* XF  = (float*)(ws + 0);               // 64 MB fp32 state [b,n,c]
    u16*   XBb = (u16*)  (ws + 67108864ull);     // 32 MB bf16 x / xn [b,n,c]
    u16*   WQt = (u16*)  (ws + 100663296ull);    // 1 MB [2][512][512]
    u16*   WKt = (u16*)  (ws + 101711872ull);    // 1 MB
    u16*   WVt = (u16*)  (ws + 102760448ull);    // 1 MB
    u16*   W1b = (u16*)  (ws + 103809024ull);    // 4 MB [2][2048][512]
    u16*   W2b = (u16*)  (ws + 108003328ull);    // 4 MB [2][512][2048]
    u16*   Mnt = (u16*)  (ws + 112197632ull);    // 1 MB [2][512][512]
    u16*   Sbf = (u16*)  (ws + 113246208ull);    // 1 MB [2][512][512]
    float* T1f = (float*)(ws + 114294784ull);    // 2 MB [2][512][512]
    float* T2f = (float*)(ws + 116391936ull);    // 2 MB
    float* QNI = (float*)(ws + 118489088ull);    // 4 KB [2][512]
    float* KNI = (float*)(ws + 118493184ull);    // 4 KB
    float* ATT = (float*)(ws + 118497280ull);    // 256 KB [2][8][64][64]

    // ---- d_out used as scratch until the final transpose ----
    u16*   R2  = (u16*)d_out;                    // 32 MB (attn phase)
    u16*   R3  = (u16*)d_out + 16777216;         // 32 MB (attn phase)
    float* Sp  = (float*)((char*)d_out + 33554432ull); // 16 MB split-K partials
    u16*   Y2  = (u16*)d_out;                    // FFN: [16384][2048] bf16 (64 MB/batch slab)

    const int BIG = 1 << 30;
    dim3 tb(32, 8);

    // prep
    transpose_k<<<dim3(512, 16, 2), tb, 0, stream>>>(x_in, XF, XBb, 512, 16384, 8388608, 8388608);
    transpose_k<<<dim3(16, 16, 2), tb, 0, stream>>>(Wq, nullptr, WQt, 512, 512, 262144, 262144);
    transpose_k<<<dim3(16, 16, 2), tb, 0, stream>>>(Wk, nullptr, WKt, 512, 512, 262144, 262144);
    transpose_k<<<dim3(16, 16, 2), tb, 0, stream>>>(Wv, nullptr, WVt, 512, 512, 262144, 262144);
    cvt_bf16_k<<<2048, 256, 0, stream>>>(w1, W1b);
    cvtw2_k<<<2048, 256, 0, stream>>>(w2, dw1, W2b);

    for (int l = 0; l < 2; l++) {
        // XT (bf16 [b][c][n]) into R2
        if (l == 0)
            cvt_bf16_k<<<16384, 256, 0, stream>>>(x_in, R2);
        else
            transpose16_k<<<dim3(16, 512, 2), tb, 0, stream>>>(XBb, R2, 16384, 512, 8388608, 8388608);
        // S = X^T X per batch: split-K partials
        gemm_nt_k<128><<<dim3(4, 8, 8), 256, 0, stream>>>(R2, R2, 16384, 16384, 512,
            512, 8388608, 2048, nullptr, nullptr, Sp, nullptr);
        sreduce_k<<<2048, 256, 0, stream>>>(Sp, Sbf);
        // T1 = S*Wq, T2 = S*Wk
        gemm_nt_k<64><<<dim3(4, 16), 256, 0, stream>>>(Sbf, WQt + l * 262144, 512, 512, 512,
            BIG, 0, 0, nullptr, nullptr, T1f, nullptr);
        gemm_nt_k<64><<<dim3(4, 16), 256, 0, stream>>>(Sbf, WKt + l * 262144, 512, 512, 512,
            BIG, 0, 0, nullptr, nullptr, T2f, nullptr);
        nrm_k<<<8, 256, 0, stream>>>(Wq + l * 262144, T1f, QNI);
        nrm_k<<<8, 256, 0, stream>>>(Wk + l * 262144, T2f, KNI);
        gsmall_k<<<dim3(8, 2), 256, 0, stream>>>(T2f, Wq + l * 262144, QNI, KNI,
            resc + l * 8, ATT);
        mbuild_k<<<dim3(8, 2), 256, 0, stream>>>(ATT, projW + l * 262144, Mnt);
        // V = x @ Wv
        gemm_nt_k<64><<<dim3(4, 512), 256, 0, stream>>>(XBb, WVt + l * 262144, 512, 512, 512,
            BIG, 0, 0, nullptr, nullptr, nullptr, R3);
        // x += V @ M^T + proj_b
        gemm_nt_k<64><<<dim3(4, 512), 256, 0, stream>>>(R3, Mnt, 512, 512, 512,
            16384, 262144, 0, projB + l * 512, XF, XF, nullptr);
        // positional branch: dwconv3+gelu -> R2, then dwconv3 accumulated into XF
        dwreg_k<3, 16, 4, true, false, false, 512, 512><<<dim3(64, 8, 2), 256, 0, stream>>>(
            R3, posw1 + l * 4608, R2, nullptr);
        dwreg_k<3, 16, 4, false, false, true, 512, 512><<<dim3(64, 8, 2), 256, 0, stream>>>(
            R2, posw2 + l * 4608, nullptr, XF);
        // PreNorm
        ln_k<<<8192, 256, 0, stream>>>(XF, lng + l * 512, lnb + l * 512, XBb);
        // MS-FFN: per-batch slabs. Y2 [16384][2048] with k-column order
        // g0|g1|g2|g3 matching W2b. Single temp slot = cols 0-511, time-
        // multiplexed (stream order makes reuse race-free); g0 lands there
        // last. ONE K=2048 down-GEMM per batch (one XF RMW pass instead of 2).
        for (int b2 = 0; b2 < 2; b2++) {
            const size_t boff = (size_t)b2 * NPIX * 512;
            const u16* w1l = W1b + l * 1048576;
            // up g3 -> temp slot, conv7 -> final cols 1536-2047
            gemm_nt_k<64><<<dim3(4, 256), 256, 0, stream>>>(XBb + boff,
                w1l + 3 * 262144, 512, 512, 2048,
                BIG, 0, 0, nullptr, nullptr, nullptr, Y2);
            dwreg_k<7, 32, 2, false, true, false, 2048, 2048><<<dim3(128, 4, 1), 256, 0, stream>>>(
                Y2, dw7 + l * 25088, Y2 + 1536, nullptr);
            // up g1 -> temp slot, conv3 -> final cols 512-1023
            gemm_nt_k<64><<<dim3(4, 256), 256, 0, stream>>>(XBb + boff,
                w1l + 1 * 262144, 512, 512, 2048,
                BIG, 0, 0, nullptr, nullptr, nullptr, Y2);
            dwreg_k<3, 16, 4, false, true, false, 2048, 2048><<<dim3(64, 8, 1), 256, 0, stream>>>(
                Y2, dw3 + l * 4608, Y2 + 512, nullptr);
            // up g2 -> temp slot, conv5 -> final cols 1024-1535
            gemm_nt_k<64><<<dim3(4, 256), 256, 0, stream>>>(XBb + boff,
                w1l + 2 * 262144, 512, 512, 2048,
                BIG, 0, 0, nullptr, nullptr, nullptr, Y2);
            dwreg_k<5, 16, 2, false, true, false, 2048, 2048><<<dim3(128, 8, 1), 256, 0, stream>>>(
                Y2, dw5 + l * 12800, Y2 + 1024, nullptr);
            // up g0 -> final cols 0-511 (1x1 dw folded into W2b prescale)
            gemm_nt_k<64><<<dim3(4, 256), 256, 0, stream>>>(XBb + boff,
                w1l + 0 * 262144, 512, 512, 2048,
                BIG, 0, 0, nullptr, nullptr, nullptr, Y2);
            // single K=2048 down-GEMM: XF += Y2 @ W2b^T, also emit bf16 x
            gemm_nt_k<64><<<dim3(4, 256), 256, 0, stream>>>(Y2,
                W2b + l * 1048576, 2048, 2048, 512,
                BIG, 0, 0, nullptr, XF + boff, XF + boff, XBb + boff);
        }
    }
    // final: XF [b,n,c] -> out [b,c,n]
    transpose_k<<<dim3(16, 512, 2), tb, 0, stream>>>(XF, out, nullptr, 16384, 512, 8388608, 8388608);
}